// Round 1
// baseline (719.780 us; speedup 1.0000x reference)
//
#include <hip/hip_runtime.h>
#include <math.h>

#define NBATCH 16384
#define EPSV 1e-5f

// ---------------------------------------------------------------------------
// K1: fully fused per-image forward. One 256-thread block per image.
// Writes pre-BN out [B,4] directly into d_out (K4 normalizes in place).
// ---------------------------------------------------------------------------
__global__ __launch_bounds__(256) void k_fused(
    const float* __restrict__ x,
    const float* __restrict__ w1, const float* __restrict__ b1,
    const float* __restrict__ w2, const float* __restrict__ b2,
    const float* __restrict__ s1w, const float* __restrict__ s1b,
    const float* __restrict__ s2w, const float* __restrict__ s2b,
    const float* __restrict__ fw, const float* __restrict__ fb,
    const float* __restrict__ fc1w, const float* __restrict__ fc1b,
    const float* __restrict__ fc2w, const float* __restrict__ fc2b,
    float* __restrict__ pre)
{
    const int b = blockIdx.x;
    const int t = threadIdx.x;

    __shared__ float sx[30][32];      // zero-padded 28x28 input (pad=1)
    __shared__ float sf1[8][16][16];  // zero-padded 14x14 conv1 output
    __shared__ float scomb[788];      // combined vector [787]
    __shared__ float sw1[72];
    __shared__ float sb1[8];
    __shared__ float sw2[1152];
    __shared__ float sb2[16];
    __shared__ float sh1[64];
    __shared__ float sred[4];
    __shared__ float ssm[27];         // s1w(8) s1b(4) s2w(8) s2b(2) fw(4) fb(1)

    // zero padded tiles + stage small weights
    for (int i = t; i < 30 * 32; i += 256) (&sx[0][0])[i] = 0.f;
    for (int i = t; i < 8 * 16 * 16; i += 256) (&sf1[0][0][0])[i] = 0.f;
    if (t < 72) sw1[t] = w1[t];
    if (t < 8) sb1[t] = b1[t];
    for (int i = t; i < 1152; i += 256) sw2[i] = w2[i];
    if (t < 16) sb2[t] = b2[t];
    if (t < 8) ssm[t] = s1w[t];
    else if (t < 12) ssm[t] = s1b[t - 8];
    else if (t < 20) ssm[t] = s2w[t - 12];
    else if (t < 22) ssm[t] = s2b[t - 20];
    else if (t < 26) ssm[t] = fw[t - 22];
    else if (t == 26) ssm[t] = fb[0];
    __syncthreads();

    // load x into padded LDS
    const float* xb = x + (size_t)b * 784;
    for (int i = t; i < 784; i += 256) {
        int r = i / 28, c = i - (i / 28) * 28;
        sx[r + 1][c + 1] = xb[i];
    }
    __syncthreads();

    // ---- conv1 (1->8, 3x3, pad 1) + relu + maxpool2 -> sf1[8][14][14] padded
    for (int i = t; i < 1568; i += 256) {
        int oc = i / 196;
        int r = i - oc * 196;
        int p = r / 14, q = r - (r / 14) * 14;
        float W[9];
        #pragma unroll
        for (int k = 0; k < 9; ++k) W[k] = sw1[oc * 9 + k];
        float X[4][4];
        #pragma unroll
        for (int u = 0; u < 4; ++u)
            #pragma unroll
            for (int v = 0; v < 4; ++v)
                X[u][v] = sx[2 * p + u][2 * q + v];
        const float bias = sb1[oc];
        float m = 0.f;  // relu then max == max(0, c0..c3)
        #pragma unroll
        for (int dr = 0; dr < 2; ++dr)
            #pragma unroll
            for (int dc = 0; dc < 2; ++dc) {
                float c0 = bias;
                #pragma unroll
                for (int u = 0; u < 3; ++u)
                    #pragma unroll
                    for (int v = 0; v < 3; ++v)
                        c0 = fmaf(X[dr + u][dc + v], W[u * 3 + v], c0);
                m = fmaxf(m, c0);
            }
        sf1[oc][p + 1][q + 1] = m;
    }
    __syncthreads();

    // ---- conv2 (8->16, 3x3, pad 1) + relu + maxpool2 -> scomb[0..783]
    for (int i = t; i < 784; i += 256) {
        int oc = i / 49;
        int r = i - oc * 49;
        int p = r / 7, q = r - (r / 7) * 7;
        const float bias = sb2[oc];
        float a0 = bias, a1 = bias, a2 = bias, a3 = bias;
        #pragma unroll
        for (int ic = 0; ic < 8; ++ic) {
            float W[9];
            #pragma unroll
            for (int k = 0; k < 9; ++k) W[k] = sw2[(oc * 8 + ic) * 9 + k];
            float X[4][4];
            #pragma unroll
            for (int u = 0; u < 4; ++u)
                #pragma unroll
                for (int v = 0; v < 4; ++v)
                    X[u][v] = sf1[ic][2 * p + u][2 * q + v];
            #pragma unroll
            for (int u = 0; u < 3; ++u)
                #pragma unroll
                for (int v = 0; v < 3; ++v) {
                    float wv = W[u * 3 + v];
                    a0 = fmaf(X[u][v], wv, a0);
                    a1 = fmaf(X[u][v + 1], wv, a1);
                    a2 = fmaf(X[u + 1][v], wv, a2);
                    a3 = fmaf(X[u + 1][v + 1], wv, a3);
                }
        }
        float m = fmaxf(fmaxf(a0, a1), fmaxf(a2, a3));
        scomb[i] = fmaxf(m, 0.f);
    }

    // ---- filter conv (2x2, no pad) + sigmoid + mean -> scomb[786]
    {
        const float fw00 = ssm[22], fw01 = ssm[23], fw10 = ssm[24], fw11 = ssm[25];
        const float fbv = ssm[26];
        float fsum = 0.f;
        for (int i = t; i < 729; i += 256) {
            int r = i / 27, c = i - (i / 27) * 27;
            float v = fbv;
            v = fmaf(sx[r + 1][c + 1], fw00, v);
            v = fmaf(sx[r + 1][c + 2], fw01, v);
            v = fmaf(sx[r + 2][c + 1], fw10, v);
            v = fmaf(sx[r + 2][c + 2], fw11, v);
            fsum += 1.f / (1.f + expf(-v));
        }
        #pragma unroll
        for (int off = 32; off > 0; off >>= 1)
            fsum += __shfl_xor(fsum, off, 64);
        if ((t & 63) == 0) sred[t >> 6] = fsum;
    }
    __syncthreads();

    // ---- sampler (thread 0) + filter mean finalize
    if (t == 0) {
        scomb[786] = (sred[0] + sred[1] + sred[2] + sred[3]) * (1.f / 729.f);
        float f0 = scomb[0], f1 = scomb[1];
        float h[4];
        #pragma unroll
        for (int k = 0; k < 4; ++k)
            h[k] = tanhf(fmaf(f0, ssm[k * 2], fmaf(f1, ssm[k * 2 + 1], ssm[8 + k])));
        float l0 = ssm[20], l1 = ssm[21];
        #pragma unroll
        for (int k = 0; k < 4; ++k) {
            l0 = fmaf(h[k], ssm[12 + k], l0);
            l1 = fmaf(h[k], ssm[16 + k], l1);
        }
        float mx = fmaxf(l0, l1);
        float e0 = expf(l0 - mx), e1 = expf(l1 - mx);
        float inv = 1.f / (e0 + e1);
        scomb[784] = e0 * inv;
        scomb[785] = e1 * inv;
    }
    __syncthreads();

    // ---- fc1: 64 outputs x 787, 4 threads per output (k strided by 4)
    {
        const int o = t >> 2, part = t & 3;
        const float* wrow = fc1w + o * 787;
        float acc = 0.f;
        for (int k = part; k < 787; k += 4)
            acc = fmaf(scomb[k], wrow[k], acc);
        acc += __shfl_xor(acc, 1, 64);
        acc += __shfl_xor(acc, 2, 64);
        if (part == 0) sh1[o] = fmaxf(acc + fc1b[o], 0.f);
    }
    __syncthreads();

    // ---- fc2: 4 outputs, one wave each (lane = k)
    {
        const int oo = t >> 6, lane = t & 63;
        float v = sh1[lane] * fc2w[oo * 64 + lane];
        #pragma unroll
        for (int off = 32; off > 0; off >>= 1)
            v += __shfl_xor(v, off, 64);
        if (lane == 0) pre[(size_t)b * 4 + oo] = v + fc2b[oo];
    }
}

// ---------------------------------------------------------------------------
// K2: per-block (256 rows) partial sum / sumsq of pre[:,0..3]
// ---------------------------------------------------------------------------
__global__ __launch_bounds__(256) void k_bnstat(const float* __restrict__ pre,
                                                float* __restrict__ part)
{
    const int t = threadIdx.x;
    const int row = blockIdx.x * 256 + t;
    float4 v = reinterpret_cast<const float4*>(pre)[row];
    float s0 = v.x, s1 = v.y, s2 = v.z, s3 = v.w;
    float q0 = v.x * v.x, q1 = v.y * v.y, q2 = v.z * v.z, q3 = v.w * v.w;
    #pragma unroll
    for (int off = 32; off > 0; off >>= 1) {
        s0 += __shfl_xor(s0, off, 64);
        s1 += __shfl_xor(s1, off, 64);
        s2 += __shfl_xor(s2, off, 64);
        s3 += __shfl_xor(s3, off, 64);
        q0 += __shfl_xor(q0, off, 64);
        q1 += __shfl_xor(q1, off, 64);
        q2 += __shfl_xor(q2, off, 64);
        q3 += __shfl_xor(q3, off, 64);
    }
    __shared__ float acc[4][8];
    if ((t & 63) == 0) {
        int w = t >> 6;
        acc[w][0] = s0; acc[w][1] = s1; acc[w][2] = s2; acc[w][3] = s3;
        acc[w][4] = q0; acc[w][5] = q1; acc[w][6] = q2; acc[w][7] = q3;
    }
    __syncthreads();
    if (t < 8)
        part[blockIdx.x * 8 + t] = acc[0][t] + acc[1][t] + acc[2][t] + acc[3][t];
}

// ---------------------------------------------------------------------------
// K3: reduce 64 partials -> scale/shift (one wave)
// ---------------------------------------------------------------------------
__global__ void k_bnfinal(const float* __restrict__ part,
                          const float* __restrict__ g, const float* __restrict__ bb,
                          float* __restrict__ ss)
{
    const int t = threadIdx.x;  // 64 threads
    float s[8];
    #pragma unroll
    for (int i = 0; i < 8; ++i) s[i] = part[t * 8 + i];
    #pragma unroll
    for (int i = 0; i < 8; ++i)
        #pragma unroll
        for (int off = 32; off > 0; off >>= 1)
            s[i] += __shfl_xor(s[i], off, 64);
    if (t == 0) {
        const float invB = 1.f / 16384.f;
        #pragma unroll
        for (int j = 0; j < 4; ++j) {
            float mu = s[j] * invB;
            float var = s[4 + j] * invB - mu * mu;
            float sc = g[j] * rsqrtf(var + EPSV);
            ss[j] = sc;
            ss[4 + j] = bb[j] - mu * sc;
        }
    }
}

// ---------------------------------------------------------------------------
// K4: in-place normalize d_out
// ---------------------------------------------------------------------------
__global__ __launch_bounds__(256) void k_bnapply(const float* __restrict__ ss,
                                                 float* __restrict__ out)
{
    const int row = blockIdx.x * 256 + threadIdx.x;
    float4 v = reinterpret_cast<float4*>(out)[row];
    v.x = fmaf(v.x, ss[0], ss[4]);
    v.y = fmaf(v.y, ss[1], ss[5]);
    v.z = fmaf(v.z, ss[2], ss[6]);
    v.w = fmaf(v.w, ss[3], ss[7]);
    reinterpret_cast<float4*>(out)[row] = v;
}

extern "C" void kernel_launch(void* const* d_in, const int* in_sizes, int n_in,
                              void* d_out, int out_size, void* d_ws, size_t ws_size,
                              hipStream_t stream)
{
    const float* x    = (const float*)d_in[0];
    const float* w1   = (const float*)d_in[1];
    const float* b1   = (const float*)d_in[2];
    const float* w2   = (const float*)d_in[3];
    const float* b2   = (const float*)d_in[4];
    const float* s1w  = (const float*)d_in[5];
    const float* s1b  = (const float*)d_in[6];
    const float* s2w  = (const float*)d_in[7];
    const float* s2b  = (const float*)d_in[8];
    const float* fw   = (const float*)d_in[9];
    const float* fb   = (const float*)d_in[10];
    const float* fc1w = (const float*)d_in[11];
    const float* fc1b = (const float*)d_in[12];
    const float* fc2w = (const float*)d_in[13];
    const float* fc2b = (const float*)d_in[14];
    const float* bng  = (const float*)d_in[15];
    const float* bnb  = (const float*)d_in[16];

    float* out  = (float*)d_out;          // pre-BN, then normalized in place
    float* part = (float*)d_ws;           // [64*8]
    float* ss   = part + 512;             // [8]

    k_fused<<<NBATCH, 256, 0, stream>>>(x, w1, b1, w2, b2, s1w, s1b, s2w, s2b,
                                        fw, fb, fc1w, fc1b, fc2w, fc2b, out);
    k_bnstat<<<64, 256, 0, stream>>>(out, part);
    k_bnfinal<<<1, 64, 0, stream>>>(part, bng, bnb, ss);
    k_bnapply<<<64, 256, 0, stream>>>(ss, out);
}

// Round 2
// 344.698 us; speedup vs baseline: 2.0881x; 2.0881x over previous
//
#include <hip/hip_runtime.h>
#include <math.h>

#define NBATCH 16384
#define EPSV 1e-5f

// sf1 layout: ic stride 324 floats (not 320) so ic doesn't alias bank 0
#define SF1(ic, r, c) sf1[(ic) * 324 + (r) * 20 + (c)]

// ---------------------------------------------------------------------------
// K0: transpose fc1w [64][787] -> wt [787][64] so fc1 loads are coalesced
// ---------------------------------------------------------------------------
__global__ __launch_bounds__(256) void k_transpose(const float* __restrict__ in,
                                                   float* __restrict__ out)
{
    int i = blockIdx.x * 256 + threadIdx.x;
    if (i < 787 * 64) {
        int k = i >> 6, o = i & 63;
        out[i] = in[o * 787 + k];
    }
}

// ---------------------------------------------------------------------------
// K1: fully fused per-image forward. One 256-thread block per image.
// ---------------------------------------------------------------------------
__global__ __launch_bounds__(256) void k_fused(
    const float* __restrict__ x,
    const float* __restrict__ w1, const float* __restrict__ b1,
    const float* __restrict__ w2, const float* __restrict__ b2,
    const float* __restrict__ s1w, const float* __restrict__ s1b,
    const float* __restrict__ s2w, const float* __restrict__ s2b,
    const float* __restrict__ fw, const float* __restrict__ fb,
    const float* __restrict__ wt, const float* __restrict__ fc1b,
    const float* __restrict__ fc2w, const float* __restrict__ fc2b,
    float* __restrict__ pre)
{
    const int b = blockIdx.x;
    const int t = threadIdx.x;

    // P[r][c] = zero-padded 30x30 input. Two 16-col-aligned copies:
    __shared__ float sxA[30][20];   // P cols 0..15
    __shared__ float sxB[30][20];   // P cols 14..29
    __shared__ float sf1[8 * 324];  // conv1 pooled out, padded 16x(14+2pad), stride 20
    __shared__ float scomb[788];
    __shared__ float sw1[72];
    __shared__ float sb1[8];
    __shared__ float sw2p[16 * 76]; // oc stride 76 (bank spread)
    __shared__ float sb2[16];
    __shared__ float sh1p[4][64];
    __shared__ float sh1[64];
    __shared__ float sred[4];
    __shared__ float ssm[27];       // s1w(8) s1b(4) s2w(8) s2b(2) fw(4) fb(1)

    // ---- zero LDS tiles + stage small weights
    for (int i = t; i < 600; i += 256) { (&sxA[0][0])[i] = 0.f; (&sxB[0][0])[i] = 0.f; }
    for (int i = t; i < 8 * 324; i += 256) sf1[i] = 0.f;
    if (t < 72) sw1[t] = w1[t];
    if (t < 8) sb1[t] = b1[t];
    for (int i = t; i < 1152; i += 256) {
        int oc = i / 72, rem = i - oc * 72;
        sw2p[oc * 76 + rem] = w2[i];
    }
    if (t < 16) sb2[t] = b2[t];
    if (t < 8) ssm[t] = s1w[t];
    else if (t < 12) ssm[t] = s1b[t - 8];
    else if (t < 20) ssm[t] = s2w[t - 12];
    else if (t < 22) ssm[t] = s2b[t - 20];
    else if (t < 26) ssm[t] = fw[t - 22];
    else if (t == 26) ssm[t] = fb[0];
    __syncthreads();

    // ---- load x into both padded copies
    const float* xb = x + (size_t)b * 784;
    for (int i = t; i < 784; i += 256) {
        int r = i / 28, c = i - (i / 28) * 28;
        float v = xb[i];
        int pr = r + 1, pc = c + 1;              // P coords
        if (pc <= 15) sxA[pr][pc] = v;
        if (pc >= 14) sxB[pr][pc - 14] = v;
    }
    __syncthreads();

    // ---- filter conv (2x2) + sigmoid partial sums (reads sx*, read-only)
    {
        const float fw00 = ssm[22], fw01 = ssm[23], fw10 = ssm[24], fw11 = ssm[25];
        const float fbv = ssm[26];
        float fsum = 0.f;
        for (int i = t; i < 729; i += 256) {
            int r = i / 27, c = i - (i / 27) * 27;
            float x00, x01, x10, x11;
            if (c <= 13) {
                x00 = sxA[r + 1][c + 1]; x01 = sxA[r + 1][c + 2];
                x10 = sxA[r + 2][c + 1]; x11 = sxA[r + 2][c + 2];
            } else {
                int cb = c - 14;
                x00 = sxB[r + 1][cb + 1]; x01 = sxB[r + 1][cb + 2];
                x10 = sxB[r + 2][cb + 1]; x11 = sxB[r + 2][cb + 2];
            }
            float v = fbv;
            v = fmaf(x00, fw00, v); v = fmaf(x01, fw01, v);
            v = fmaf(x10, fw10, v); v = fmaf(x11, fw11, v);
            fsum += 1.f / (1.f + expf(-v));
        }
        #pragma unroll
        for (int off = 32; off > 0; off >>= 1)
            fsum += __shfl_xor(fsum, off, 64);
        if ((t & 63) == 0) sred[t >> 6] = fsum;
    }

    // ---- conv1 (1->8, 3x3, pad1) + relu + maxpool -> sf1 (pooled 14x14)
    // threads: half = t>>7, id = t&127 (<112): p = id>>3 (0..13), oc = id&7
    {
        const int half = t >> 7;
        const int id = t & 127;
        if (id < 112) {
            const int p = id >> 3, oc = id & 7;
            const float* base = half ? &sxB[0][0] : &sxA[0][0];
            float X[4][16];
            #pragma unroll
            for (int u = 0; u < 4; ++u) {
                const float4* rp = reinterpret_cast<const float4*>(base + (2 * p + u) * 20);
                float4 a = rp[0], bb4 = rp[1], c4 = rp[2], d4 = rp[3];
                X[u][0] = a.x;  X[u][1] = a.y;  X[u][2] = a.z;  X[u][3] = a.w;
                X[u][4] = bb4.x; X[u][5] = bb4.y; X[u][6] = bb4.z; X[u][7] = bb4.w;
                X[u][8] = c4.x;  X[u][9] = c4.y;  X[u][10] = c4.z; X[u][11] = c4.w;
                X[u][12] = d4.x; X[u][13] = d4.y; X[u][14] = d4.z; X[u][15] = d4.w;
            }
            float W[9];
            #pragma unroll
            for (int k = 0; k < 9; ++k) W[k] = sw1[oc * 9 + k];
            const float bias = sb1[oc];
            const int j0 = half * 7;
            #pragma unroll
            for (int jj = 0; jj < 7; ++jj) {
                float m = 0.f;
                #pragma unroll
                for (int dr = 0; dr < 2; ++dr)
                    #pragma unroll
                    for (int dc = 0; dc < 2; ++dc) {
                        float acc = bias;
                        #pragma unroll
                        for (int u = 0; u < 3; ++u)
                            #pragma unroll
                            for (int v = 0; v < 3; ++v)
                                acc = fmaf(X[dr + u][2 * jj + dc + v], W[u * 3 + v], acc);
                        m = fmaxf(m, acc);
                    }
                SF1(oc, p + 1, j0 + jj + 1) = m;
            }
        }
    }
    __syncthreads();

    // ---- conv2 (8->16) + relu + maxpool -> scomb[0..783]
    // threads 0..111: p = t>>4 (0..6), oc = t&15
    if (t < 112) {
        const int p = t >> 4, oc = t & 15;
        const float bias = sb2[oc];
        float acc[7][4];
        #pragma unroll
        for (int jj = 0; jj < 7; ++jj)
            #pragma unroll
            for (int s = 0; s < 4; ++s) acc[jj][s] = bias;
        for (int ic = 0; ic < 8; ++ic) {
            float X[4][16];
            #pragma unroll
            for (int u = 0; u < 4; ++u) {
                const float4* rp = reinterpret_cast<const float4*>(&SF1(ic, 2 * p + u, 0));
                float4 a = rp[0], bb4 = rp[1], c4 = rp[2], d4 = rp[3];
                X[u][0] = a.x;  X[u][1] = a.y;  X[u][2] = a.z;  X[u][3] = a.w;
                X[u][4] = bb4.x; X[u][5] = bb4.y; X[u][6] = bb4.z; X[u][7] = bb4.w;
                X[u][8] = c4.x;  X[u][9] = c4.y;  X[u][10] = c4.z; X[u][11] = c4.w;
                X[u][12] = d4.x; X[u][13] = d4.y; X[u][14] = d4.z; X[u][15] = d4.w;
            }
            float W[9];
            #pragma unroll
            for (int k = 0; k < 9; ++k) W[k] = sw2p[oc * 76 + ic * 9 + k];
            #pragma unroll
            for (int jj = 0; jj < 7; ++jj)
                #pragma unroll
                for (int dr = 0; dr < 2; ++dr)
                    #pragma unroll
                    for (int dc = 0; dc < 2; ++dc)
                        #pragma unroll
                        for (int u = 0; u < 3; ++u)
                            #pragma unroll
                            for (int v = 0; v < 3; ++v)
                                acc[jj][dr * 2 + dc] =
                                    fmaf(X[dr + u][2 * jj + dc + v], W[u * 3 + v], acc[jj][dr * 2 + dc]);
        }
        #pragma unroll
        for (int jj = 0; jj < 7; ++jj) {
            float m = fmaxf(fmaxf(acc[jj][0], acc[jj][1]), fmaxf(acc[jj][2], acc[jj][3]));
            scomb[oc * 49 + p * 7 + jj] = fmaxf(m, 0.f);
        }
    }
    __syncthreads();

    // ---- sampler (thread 0) + filter mean finalize
    if (t == 0) {
        scomb[786] = (sred[0] + sred[1] + sred[2] + sred[3]) * (1.f / 729.f);
        float f0 = scomb[0], f1 = scomb[1];
        float h[4];
        #pragma unroll
        for (int k = 0; k < 4; ++k)
            h[k] = tanhf(fmaf(f0, ssm[k * 2], fmaf(f1, ssm[k * 2 + 1], ssm[8 + k])));
        float l0 = ssm[20], l1 = ssm[21];
        #pragma unroll
        for (int k = 0; k < 4; ++k) {
            l0 = fmaf(h[k], ssm[12 + k], l0);
            l1 = fmaf(h[k], ssm[16 + k], l1);
        }
        float mx = fmaxf(l0, l1);
        float e0 = expf(l0 - mx), e1 = expf(l1 - mx);
        float inv = 1.f / (e0 + e1);
        scomb[784] = e0 * inv;
        scomb[785] = e1 * inv;
    }
    __syncthreads();

    // ---- fc1: o = t&63, wave w covers k in [w*197, ...): coalesced wt loads
    {
        const int o = t & 63, w = t >> 6;
        const int k0 = w * 197;
        const int k1 = (w == 3) ? 787 : k0 + 197;
        const float* wp = wt + (size_t)k0 * 64 + o;
        float acc = 0.f;
        #pragma unroll 4
        for (int k = k0; k < k1; ++k) {
            acc = fmaf(scomb[k], *wp, acc);
            wp += 64;
        }
        sh1p[w][o] = acc;
    }
    __syncthreads();
    if (t < 64)
        sh1[t] = fmaxf(sh1p[0][t] + sh1p[1][t] + sh1p[2][t] + sh1p[3][t] + fc1b[t], 0.f);
    __syncthreads();

    // ---- fc2: 4 outputs, one wave each
    {
        const int oo = t >> 6, lane = t & 63;
        float v = sh1[lane] * fc2w[oo * 64 + lane];
        #pragma unroll
        for (int off = 32; off > 0; off >>= 1)
            v += __shfl_xor(v, off, 64);
        if (lane == 0) pre[(size_t)b * 4 + oo] = v + fc2b[oo];
    }
}

// ---------------------------------------------------------------------------
// K2: per-block (256 rows) partial sum / sumsq
// ---------------------------------------------------------------------------
__global__ __launch_bounds__(256) void k_bnstat(const float* __restrict__ pre,
                                                float* __restrict__ part)
{
    const int t = threadIdx.x;
    const int row = blockIdx.x * 256 + t;
    float4 v = reinterpret_cast<const float4*>(pre)[row];
    float s0 = v.x, s1 = v.y, s2 = v.z, s3 = v.w;
    float q0 = v.x * v.x, q1 = v.y * v.y, q2 = v.z * v.z, q3 = v.w * v.w;
    #pragma unroll
    for (int off = 32; off > 0; off >>= 1) {
        s0 += __shfl_xor(s0, off, 64);
        s1 += __shfl_xor(s1, off, 64);
        s2 += __shfl_xor(s2, off, 64);
        s3 += __shfl_xor(s3, off, 64);
        q0 += __shfl_xor(q0, off, 64);
        q1 += __shfl_xor(q1, off, 64);
        q2 += __shfl_xor(q2, off, 64);
        q3 += __shfl_xor(q3, off, 64);
    }
    __shared__ float acc[4][8];
    if ((t & 63) == 0) {
        int w = t >> 6;
        acc[w][0] = s0; acc[w][1] = s1; acc[w][2] = s2; acc[w][3] = s3;
        acc[w][4] = q0; acc[w][5] = q1; acc[w][6] = q2; acc[w][7] = q3;
    }
    __syncthreads();
    if (t < 8)
        part[blockIdx.x * 8 + t] = acc[0][t] + acc[1][t] + acc[2][t] + acc[3][t];
}

__global__ void k_bnfinal(const float* __restrict__ part,
                          const float* __restrict__ g, const float* __restrict__ bb,
                          float* __restrict__ ss)
{
    const int t = threadIdx.x;  // 64
    float s[8];
    #pragma unroll
    for (int i = 0; i < 8; ++i) s[i] = part[t * 8 + i];
    #pragma unroll
    for (int i = 0; i < 8; ++i)
        #pragma unroll
        for (int off = 32; off > 0; off >>= 1)
            s[i] += __shfl_xor(s[i], off, 64);
    if (t == 0) {
        const float invB = 1.f / 16384.f;
        #pragma unroll
        for (int j = 0; j < 4; ++j) {
            float mu = s[j] * invB;
            float var = s[4 + j] * invB - mu * mu;
            float sc = g[j] * rsqrtf(var + EPSV);
            ss[j] = sc;
            ss[4 + j] = bb[j] - mu * sc;
        }
    }
}

__global__ __launch_bounds__(256) void k_bnapply(const float* __restrict__ ss,
                                                 float* __restrict__ out)
{
    const int row = blockIdx.x * 256 + threadIdx.x;
    float4 v = reinterpret_cast<float4*>(out)[row];
    v.x = fmaf(v.x, ss[0], ss[4]);
    v.y = fmaf(v.y, ss[1], ss[5]);
    v.z = fmaf(v.z, ss[2], ss[6]);
    v.w = fmaf(v.w, ss[3], ss[7]);
    reinterpret_cast<float4*>(out)[row] = v;
}

extern "C" void kernel_launch(void* const* d_in, const int* in_sizes, int n_in,
                              void* d_out, int out_size, void* d_ws, size_t ws_size,
                              hipStream_t stream)
{
    const float* x    = (const float*)d_in[0];
    const float* w1   = (const float*)d_in[1];
    const float* b1   = (const float*)d_in[2];
    const float* w2   = (const float*)d_in[3];
    const float* b2   = (const float*)d_in[4];
    const float* s1w  = (const float*)d_in[5];
    const float* s1b  = (const float*)d_in[6];
    const float* s2w  = (const float*)d_in[7];
    const float* s2b  = (const float*)d_in[8];
    const float* fw   = (const float*)d_in[9];
    const float* fb   = (const float*)d_in[10];
    const float* fc1w = (const float*)d_in[11];
    const float* fc1b = (const float*)d_in[12];
    const float* fc2w = (const float*)d_in[13];
    const float* fc2b = (const float*)d_in[14];
    const float* bng  = (const float*)d_in[15];
    const float* bnb  = (const float*)d_in[16];

    float* out  = (float*)d_out;
    float* part = (float*)d_ws;           // [512]
    float* ss   = part + 512;             // [8]
    float* wt   = ss + 8;                 // [787*64]

    k_transpose<<<197, 256, 0, stream>>>(fc1w, wt);
    k_fused<<<NBATCH, 256, 0, stream>>>(x, w1, b1, w2, b2, s1w, s1b, s2w, s2b,
                                        fw, fb, wt, fc1b, fc2w, fc2b, out);
    k_bnstat<<<64, 256, 0, stream>>>(out, part);
    k_bnfinal<<<1, 64, 0, stream>>>(part, bng, bnb, ss);
    k_bnapply<<<64, 256, 0, stream>>>(ss, out);
}

// Round 3
// 276.721 us; speedup vs baseline: 2.6011x; 1.2457x over previous
//
#include <hip/hip_runtime.h>
#include <math.h>

#define NBATCH 16384
#define EPSV 1e-5f

typedef short short8 __attribute__((ext_vector_type(8)));
typedef float f32x4 __attribute__((ext_vector_type(4)));
union V8 { uint4 u; short8 s; };

__device__ __forceinline__ unsigned short f2bf(float f) {
    unsigned int x = __float_as_uint(f);
    return (unsigned short)((x + 0x7fffu + ((x >> 16) & 1u)) >> 16);  // RNE
}

// ---------------------------------------------------------------------------
// K0: fc1w [64][787] fp32 -> wt_bf16 [64][800] (K zero-padded)
// ---------------------------------------------------------------------------
__global__ __launch_bounds__(256) void k_prep(const float* __restrict__ fc1w,
                                              unsigned short* __restrict__ wt)
{
    int i = blockIdx.x * 256 + threadIdx.x;
    if (i < 64 * 800) {
        int n = i / 800, k = i - n * 800;
        float v = (k < 787) ? fc1w[n * 787 + k] : 0.f;
        wt[i] = f2bf(v);
    }
}

// ---------------------------------------------------------------------------
// K1: per-image conv1+conv2+filter+sampler -> combined bf16 [B][800] in ws
// ---------------------------------------------------------------------------
#define SF1I(ic, r, c) (((ic) * 16 + (r)) * 24 + (c))   // ushort index, row stride 24

__global__ __launch_bounds__(256) void k_conv(
    const float* __restrict__ x,
    const float* __restrict__ w1, const float* __restrict__ b1,
    const float* __restrict__ w2, const float* __restrict__ b2,
    const float* __restrict__ s1w, const float* __restrict__ s1b,
    const float* __restrict__ s2w, const float* __restrict__ s2b,
    const float* __restrict__ fw, const float* __restrict__ fb,
    unsigned short* __restrict__ comb)
{
    const int b = blockIdx.x;
    const int t = threadIdx.x;

    __shared__ float sxA[30][20];            // P cols 0..15 (zero-padded 30x30 input)
    __shared__ float sxB[30][20];            // P cols 14..29
    __shared__ unsigned short sf1[8 * 16 * 24];  // conv1 pooled out, bf16, stride 24
    __shared__ float scomb[800];
    __shared__ float sw1[72];
    __shared__ float sb1[8];
    __shared__ float sw2p[16 * 76];
    __shared__ float sb2[16];
    __shared__ float sred[4];
    __shared__ float ssm[27];                // s1w(8) s1b(4) s2w(8) s2b(2) fw(4) fb(1)

    // ---- zero tiles + stage small weights
    for (int i = t; i < 600; i += 256) { (&sxA[0][0])[i] = 0.f; (&sxB[0][0])[i] = 0.f; }
    {
        unsigned int* z = reinterpret_cast<unsigned int*>(sf1);
        for (int i = t; i < 8 * 16 * 12; i += 256) z[i] = 0u;
    }
    if (t < 16) scomb[784 + t] = 0.f;
    if (t < 72) sw1[t] = w1[t];
    if (t < 8) sb1[t] = b1[t];
    for (int i = t; i < 1152; i += 256) {
        int oc = i / 72, rem = i - oc * 72;
        sw2p[oc * 76 + rem] = w2[i];
    }
    if (t < 16) sb2[t] = b2[t];
    if (t < 8) ssm[t] = s1w[t];
    else if (t < 12) ssm[t] = s1b[t - 8];
    else if (t < 20) ssm[t] = s2w[t - 12];
    else if (t < 22) ssm[t] = s2b[t - 20];
    else if (t < 26) ssm[t] = fw[t - 22];
    else if (t == 26) ssm[t] = fb[0];
    __syncthreads();

    // ---- load x into both padded copies
    const float* xb = x + (size_t)b * 784;
    for (int i = t; i < 784; i += 256) {
        int r = i / 28, c = i - (i / 28) * 28;
        float v = xb[i];
        int pr = r + 1, pc = c + 1;
        if (pc <= 15) sxA[pr][pc] = v;
        if (pc >= 14) sxB[pr][pc - 14] = v;
    }
    __syncthreads();

    // ---- filter conv (2x2) + sigmoid partial sums
    {
        const float fw00 = ssm[22], fw01 = ssm[23], fw10 = ssm[24], fw11 = ssm[25];
        const float fbv = ssm[26];
        float fsum = 0.f;
        for (int i = t; i < 729; i += 256) {
            int r = i / 27, c = i - (i / 27) * 27;
            float x00, x01, x10, x11;
            if (c <= 13) {
                x00 = sxA[r + 1][c + 1]; x01 = sxA[r + 1][c + 2];
                x10 = sxA[r + 2][c + 1]; x11 = sxA[r + 2][c + 2];
            } else {
                int cb = c - 14;
                x00 = sxB[r + 1][cb + 1]; x01 = sxB[r + 1][cb + 2];
                x10 = sxB[r + 2][cb + 1]; x11 = sxB[r + 2][cb + 2];
            }
            float v = fbv;
            v = fmaf(x00, fw00, v); v = fmaf(x01, fw01, v);
            v = fmaf(x10, fw10, v); v = fmaf(x11, fw11, v);
            fsum += 1.f / (1.f + expf(-v));
        }
        #pragma unroll
        for (int off = 32; off > 0; off >>= 1)
            fsum += __shfl_xor(fsum, off, 64);
        if ((t & 63) == 0) sred[t >> 6] = fsum;
    }

    // ---- conv1 (1->8) + relu + maxpool -> sf1 bf16 (pooled 14x14, +1 pad)
    {
        const int half = t >> 7;
        const int id = t & 127;
        if (id < 112) {
            const int p = id >> 3, oc = id & 7;
            const float* base = half ? &sxB[0][0] : &sxA[0][0];
            float X[4][16];
            #pragma unroll
            for (int u = 0; u < 4; ++u) {
                const float4* rp = reinterpret_cast<const float4*>(base + (2 * p + u) * 20);
                float4 a = rp[0], bb4 = rp[1], c4 = rp[2], d4 = rp[3];
                X[u][0] = a.x;  X[u][1] = a.y;  X[u][2] = a.z;  X[u][3] = a.w;
                X[u][4] = bb4.x; X[u][5] = bb4.y; X[u][6] = bb4.z; X[u][7] = bb4.w;
                X[u][8] = c4.x;  X[u][9] = c4.y;  X[u][10] = c4.z; X[u][11] = c4.w;
                X[u][12] = d4.x; X[u][13] = d4.y; X[u][14] = d4.z; X[u][15] = d4.w;
            }
            float W[9];
            #pragma unroll
            for (int k = 0; k < 9; ++k) W[k] = sw1[oc * 9 + k];
            const float bias = sb1[oc];
            const int j0 = half * 7;
            #pragma unroll
            for (int jj = 0; jj < 7; ++jj) {
                float m = 0.f;
                #pragma unroll
                for (int dr = 0; dr < 2; ++dr)
                    #pragma unroll
                    for (int dc = 0; dc < 2; ++dc) {
                        float acc = bias;
                        #pragma unroll
                        for (int u = 0; u < 3; ++u)
                            #pragma unroll
                            for (int v = 0; v < 3; ++v)
                                acc = fmaf(X[dr + u][2 * jj + dc + v], W[u * 3 + v], acc);
                        m = fmaxf(m, acc);
                    }
                sf1[SF1I(oc, p + 1, j0 + jj + 1)] = f2bf(m);
            }
        }
    }
    __syncthreads();

    // ---- conv2 (8->16) + relu + maxpool -> scomb[0..783]
    if (t < 112) {
        const int p = t >> 4, oc = t & 15;
        const float bias = sb2[oc];
        float acc[7][4];
        #pragma unroll
        for (int jj = 0; jj < 7; ++jj)
            #pragma unroll
            for (int s = 0; s < 4; ++s) acc[jj][s] = bias;
        for (int ic = 0; ic < 8; ++ic) {
            float X[4][16];
            #pragma unroll
            for (int u = 0; u < 4; ++u) {
                const uint4* rp = reinterpret_cast<const uint4*>(&sf1[SF1I(ic, 2 * p + u, 0)]);
                uint4 q0 = rp[0], q1 = rp[1];
                X[u][0]  = __uint_as_float(q0.x << 16); X[u][1]  = __uint_as_float(q0.x & 0xffff0000u);
                X[u][2]  = __uint_as_float(q0.y << 16); X[u][3]  = __uint_as_float(q0.y & 0xffff0000u);
                X[u][4]  = __uint_as_float(q0.z << 16); X[u][5]  = __uint_as_float(q0.z & 0xffff0000u);
                X[u][6]  = __uint_as_float(q0.w << 16); X[u][7]  = __uint_as_float(q0.w & 0xffff0000u);
                X[u][8]  = __uint_as_float(q1.x << 16); X[u][9]  = __uint_as_float(q1.x & 0xffff0000u);
                X[u][10] = __uint_as_float(q1.y << 16); X[u][11] = __uint_as_float(q1.y & 0xffff0000u);
                X[u][12] = __uint_as_float(q1.z << 16); X[u][13] = __uint_as_float(q1.z & 0xffff0000u);
                X[u][14] = __uint_as_float(q1.w << 16); X[u][15] = __uint_as_float(q1.w & 0xffff0000u);
            }
            float W[9];
            #pragma unroll
            for (int k = 0; k < 9; ++k) W[k] = sw2p[oc * 76 + ic * 9 + k];
            #pragma unroll
            for (int jj = 0; jj < 7; ++jj)
                #pragma unroll
                for (int dr = 0; dr < 2; ++dr)
                    #pragma unroll
                    for (int dc = 0; dc < 2; ++dc)
                        #pragma unroll
                        for (int u = 0; u < 3; ++u)
                            #pragma unroll
                            for (int v = 0; v < 3; ++v)
                                acc[jj][dr * 2 + dc] =
                                    fmaf(X[dr + u][2 * jj + dc + v], W[u * 3 + v], acc[jj][dr * 2 + dc]);
        }
        #pragma unroll
        for (int jj = 0; jj < 7; ++jj) {
            float m = fmaxf(fmaxf(acc[jj][0], acc[jj][1]), fmaxf(acc[jj][2], acc[jj][3]));
            scomb[oc * 49 + p * 7 + jj] = fmaxf(m, 0.f);
        }
    }
    __syncthreads();

    // ---- sampler (thread 0) + filter mean finalize
    if (t == 0) {
        scomb[786] = (sred[0] + sred[1] + sred[2] + sred[3]) * (1.f / 729.f);
        float f0 = scomb[0], f1 = scomb[1];
        float h[4];
        #pragma unroll
        for (int k = 0; k < 4; ++k)
            h[k] = tanhf(fmaf(f0, ssm[k * 2], fmaf(f1, ssm[k * 2 + 1], ssm[8 + k])));
        float l0 = ssm[20], l1 = ssm[21];
        #pragma unroll
        for (int k = 0; k < 4; ++k) {
            l0 = fmaf(h[k], ssm[12 + k], l0);
            l1 = fmaf(h[k], ssm[16 + k], l1);
        }
        float mx = fmaxf(l0, l1);
        float e0 = expf(l0 - mx), e1 = expf(l1 - mx);
        float inv = 1.f / (e0 + e1);
        scomb[784] = e0 * inv;
        scomb[785] = e1 * inv;
    }
    __syncthreads();

    // ---- pack scomb -> combined bf16 row [800]
    if (t < 100) {
        const float4* sp = reinterpret_cast<const float4*>(scomb);
        float4 f0 = sp[2 * t], f1 = sp[2 * t + 1];
        uint4 o;
        o.x = (unsigned int)f2bf(f0.x) | ((unsigned int)f2bf(f0.y) << 16);
        o.y = (unsigned int)f2bf(f0.z) | ((unsigned int)f2bf(f0.w) << 16);
        o.z = (unsigned int)f2bf(f1.x) | ((unsigned int)f2bf(f1.y) << 16);
        o.w = (unsigned int)f2bf(f1.z) | ((unsigned int)f2bf(f1.w) << 16);
        reinterpret_cast<uint4*>(comb)[(size_t)b * 100 + t] = o;
    }
}

// ---------------------------------------------------------------------------
// K2: MFMA GEMM  h1 = relu(comb[16384,800] @ wt[64,800]^T + fc1b)
//     epilogue: out = h1 @ fc2w^T + fc2b  (+ per-block BN partial stats)
//     block = 64 rows, 4 waves (wave w: rows 16w..16w+15, all 64 cols)
// ---------------------------------------------------------------------------
__global__ __launch_bounds__(256) void k_fc(
    const unsigned short* __restrict__ A,   // [16384][800] bf16
    const unsigned short* __restrict__ Bw,  // [64][800] bf16
    const float* __restrict__ fc1b,
    const float* __restrict__ fc2w, const float* __restrict__ fc2b,
    float* __restrict__ out, float* __restrict__ part)
{
    __shared__ uint4 Asm[2][256];   // [buf][row*4 + kb_phys], kb_phys = kb ^ ((row>>1)&3)
    __shared__ uint4 Bsm[2][256];
    __shared__ float sh[64][68];
    __shared__ float sfc2[4][64];
    __shared__ float pacc[4][8];

    const int t = threadIdx.x;
    const int w = t >> 6, l = t & 63;
    const int blk = blockIdx.x;

    sfc2[t >> 6][t & 63] = fc2w[t];

    // staging map: row = t>>2, kb_phys = t&3 (contiguous LDS writes)
    const int srow = t >> 2, skbp = t & 3;
    const int skbl = skbp ^ ((srow >> 1) & 3);
    const uint4* Ag = reinterpret_cast<const uint4*>(A) + ((size_t)blk * 64 + srow) * 100;
    const uint4* Bg = reinterpret_cast<const uint4*>(Bw) + (size_t)srow * 100;
    const int sidx = srow * 4 + skbp;

    // read map (constant across k-steps)
    const int arow = w * 16 + (l & 15);
    const int aidx = arow * 4 + ((l >> 4) ^ ((arow >> 1) & 3));
    int bidx[4];
    #pragma unroll
    for (int nf = 0; nf < 4; ++nf) {
        int n = nf * 16 + (l & 15);
        bidx[nf] = n * 4 + ((l >> 4) ^ ((n >> 1) & 3));
    }

    f32x4 acc0 = {0.f, 0.f, 0.f, 0.f}, acc1 = acc0, acc2 = acc0, acc3 = acc0;

    // prologue: stage k-step 0
    Asm[0][sidx] = Ag[skbl];
    Bsm[0][sidx] = Bg[skbl];

    int buf = 0;
    for (int s = 0; s < 25; ++s) {
        __syncthreads();
        if (s < 24) {
            Asm[buf ^ 1][sidx] = Ag[(s + 1) * 4 + skbl];
            Bsm[buf ^ 1][sidx] = Bg[(s + 1) * 4 + skbl];
        }
        V8 av; av.u = Asm[buf][aidx];
        V8 b0; b0.u = Bsm[buf][bidx[0]];
        V8 b1; b1.u = Bsm[buf][bidx[1]];
        V8 b2; b2.u = Bsm[buf][bidx[2]];
        V8 b3; b3.u = Bsm[buf][bidx[3]];
        acc0 = __builtin_amdgcn_mfma_f32_16x16x32_bf16(av.s, b0.s, acc0, 0, 0, 0);
        acc1 = __builtin_amdgcn_mfma_f32_16x16x32_bf16(av.s, b1.s, acc1, 0, 0, 0);
        acc2 = __builtin_amdgcn_mfma_f32_16x16x32_bf16(av.s, b2.s, acc2, 0, 0, 0);
        acc3 = __builtin_amdgcn_mfma_f32_16x16x32_bf16(av.s, b3.s, acc3, 0, 0, 0);
        buf ^= 1;
    }

    // epilogue: relu(acc + fc1b) -> sh ;  C layout: row=(l>>4)*4+r, col=l&15
    {
        const int c0 = l & 15, r0 = w * 16 + (l >> 4) * 4;
        float fb0 = fc1b[c0], fb1 = fc1b[16 + c0], fb2 = fc1b[32 + c0], fb3 = fc1b[48 + c0];
        #pragma unroll
        for (int r = 0; r < 4; ++r) {
            sh[r0 + r][c0]      = fmaxf(acc0[r] + fb0, 0.f);
            sh[r0 + r][16 + c0] = fmaxf(acc1[r] + fb1, 0.f);
            sh[r0 + r][32 + c0] = fmaxf(acc2[r] + fb2, 0.f);
            sh[r0 + r][48 + c0] = fmaxf(acc3[r] + fb3, 0.f);
        }
    }
    __syncthreads();

    // fc2: t -> (row = t>>2, oo = t&3)
    {
        const int row = t >> 2, oo = t & 3;
        float s = fc2b[oo];
        #pragma unroll 8
        for (int o = 0; o < 64; ++o)
            s = fmaf(sh[row][o], sfc2[oo][o], s);
        out[((size_t)blk * 64 + row) * 4 + oo] = s;

        // BN partial stats: reduce over rows within wave (lanes with same oo)
        float rs = s, rq = s * s;
        #pragma unroll
        for (int off = 4; off < 64; off <<= 1) {
            rs += __shfl_xor(rs, off, 64);
            rq += __shfl_xor(rq, off, 64);
        }
        if (l < 4) pacc[w][l] = rs;
        else if (l < 8) pacc[w][l] = rq;
    }
    __syncthreads();
    if (t < 8)
        part[blk * 8 + t] = pacc[0][t] + pacc[1][t] + pacc[2][t] + pacc[3][t];
}

// ---------------------------------------------------------------------------
// BN finalize (nblocks partials) + apply
// ---------------------------------------------------------------------------
__global__ void k_bnfinal(const float* __restrict__ part,
                          const float* __restrict__ g, const float* __restrict__ bb,
                          float* __restrict__ ss, int nblocks)
{
    const int t = threadIdx.x;  // 64
    float s[8];
    #pragma unroll
    for (int i = 0; i < 8; ++i) s[i] = 0.f;
    for (int idx = t; idx < nblocks; idx += 64)
        #pragma unroll
        for (int i = 0; i < 8; ++i) s[i] += part[idx * 8 + i];
    #pragma unroll
    for (int i = 0; i < 8; ++i)
        #pragma unroll
        for (int off = 32; off > 0; off >>= 1)
            s[i] += __shfl_xor(s[i], off, 64);
    if (t == 0) {
        const float invB = 1.f / 16384.f;
        #pragma unroll
        for (int j = 0; j < 4; ++j) {
            float mu = s[j] * invB;
            float var = s[4 + j] * invB - mu * mu;
            float sc = g[j] * rsqrtf(var + EPSV);
            ss[j] = sc;
            ss[4 + j] = bb[j] - mu * sc;
        }
    }
}

__global__ __launch_bounds__(256) void k_bnapply(const float* __restrict__ ss,
                                                 float* __restrict__ out)
{
    const int row = blockIdx.x * 256 + threadIdx.x;
    float4 v = reinterpret_cast<float4*>(out)[row];
    v.x = fmaf(v.x, ss[0], ss[4]);
    v.y = fmaf(v.y, ss[1], ss[5]);
    v.z = fmaf(v.z, ss[2], ss[6]);
    v.w = fmaf(v.w, ss[3], ss[7]);
    reinterpret_cast<float4*>(out)[row] = v;
}

// ===========================================================================
// Fallback path (round-2 kernels) — used if ws_size is too small for comb
// ===========================================================================
__global__ __launch_bounds__(256) void k_transpose_fb(const float* __restrict__ in,
                                                      float* __restrict__ out)
{
    int i = blockIdx.x * 256 + threadIdx.x;
    if (i < 787 * 64) {
        int k = i >> 6, o = i & 63;
        out[i] = in[o * 787 + k];
    }
}

#define SF1F(ic, r, c) sf1[(ic) * 324 + (r) * 20 + (c)]

__global__ __launch_bounds__(256) void k_fused_fb(
    const float* __restrict__ x,
    const float* __restrict__ w1, const float* __restrict__ b1,
    const float* __restrict__ w2, const float* __restrict__ b2,
    const float* __restrict__ s1w, const float* __restrict__ s1b,
    const float* __restrict__ s2w, const float* __restrict__ s2b,
    const float* __restrict__ fw, const float* __restrict__ fb,
    const float* __restrict__ wt, const float* __restrict__ fc1b,
    const float* __restrict__ fc2w, const float* __restrict__ fc2b,
    float* __restrict__ pre)
{
    const int b = blockIdx.x;
    const int t = threadIdx.x;

    __shared__ float sxA[30][20];
    __shared__ float sxB[30][20];
    __shared__ float sf1[8 * 324];
    __shared__ float scomb[788];
    __shared__ float sw1[72];
    __shared__ float sb1[8];
    __shared__ float sw2p[16 * 76];
    __shared__ float sb2[16];
    __shared__ float sh1p[4][64];
    __shared__ float sh1[64];
    __shared__ float sred[4];
    __shared__ float ssm[27];

    for (int i = t; i < 600; i += 256) { (&sxA[0][0])[i] = 0.f; (&sxB[0][0])[i] = 0.f; }
    for (int i = t; i < 8 * 324; i += 256) sf1[i] = 0.f;
    if (t < 72) sw1[t] = w1[t];
    if (t < 8) sb1[t] = b1[t];
    for (int i = t; i < 1152; i += 256) {
        int oc = i / 72, rem = i - oc * 72;
        sw2p[oc * 76 + rem] = w2[i];
    }
    if (t < 16) sb2[t] = b2[t];
    if (t < 8) ssm[t] = s1w[t];
    else if (t < 12) ssm[t] = s1b[t - 8];
    else if (t < 20) ssm[t] = s2w[t - 12];
    else if (t < 22) ssm[t] = s2b[t - 20];
    else if (t < 26) ssm[t] = fw[t - 22];
    else if (t == 26) ssm[t] = fb[0];
    __syncthreads();

    const float* xb = x + (size_t)b * 784;
    for (int i = t; i < 784; i += 256) {
        int r = i / 28, c = i - (i / 28) * 28;
        float v = xb[i];
        int pr = r + 1, pc = c + 1;
        if (pc <= 15) sxA[pr][pc] = v;
        if (pc >= 14) sxB[pr][pc - 14] = v;
    }
    __syncthreads();

    {
        const float fw00 = ssm[22], fw01 = ssm[23], fw10 = ssm[24], fw11 = ssm[25];
        const float fbv = ssm[26];
        float fsum = 0.f;
        for (int i = t; i < 729; i += 256) {
            int r = i / 27, c = i - (i / 27) * 27;
            float x00, x01, x10, x11;
            if (c <= 13) {
                x00 = sxA[r + 1][c + 1]; x01 = sxA[r + 1][c + 2];
                x10 = sxA[r + 2][c + 1]; x11 = sxA[r + 2][c + 2];
            } else {
                int cb = c - 14;
                x00 = sxB[r + 1][cb + 1]; x01 = sxB[r + 1][cb + 2];
                x10 = sxB[r + 2][cb + 1]; x11 = sxB[r + 2][cb + 2];
            }
            float v = fbv;
            v = fmaf(x00, fw00, v); v = fmaf(x01, fw01, v);
            v = fmaf(x10, fw10, v); v = fmaf(x11, fw11, v);
            fsum += 1.f / (1.f + expf(-v));
        }
        #pragma unroll
        for (int off = 32; off > 0; off >>= 1)
            fsum += __shfl_xor(fsum, off, 64);
        if ((t & 63) == 0) sred[t >> 6] = fsum;
    }

    {
        const int half = t >> 7;
        const int id = t & 127;
        if (id < 112) {
            const int p = id >> 3, oc = id & 7;
            const float* base = half ? &sxB[0][0] : &sxA[0][0];
            float X[4][16];
            #pragma unroll
            for (int u = 0; u < 4; ++u) {
                const float4* rp = reinterpret_cast<const float4*>(base + (2 * p + u) * 20);
                float4 a = rp[0], bb4 = rp[1], c4 = rp[2], d4 = rp[3];
                X[u][0] = a.x;  X[u][1] = a.y;  X[u][2] = a.z;  X[u][3] = a.w;
                X[u][4] = bb4.x; X[u][5] = bb4.y; X[u][6] = bb4.z; X[u][7] = bb4.w;
                X[u][8] = c4.x;  X[u][9] = c4.y;  X[u][10] = c4.z; X[u][11] = c4.w;
                X[u][12] = d4.x; X[u][13] = d4.y; X[u][14] = d4.z; X[u][15] = d4.w;
            }
            float W[9];
            #pragma unroll
            for (int k = 0; k < 9; ++k) W[k] = sw1[oc * 9 + k];
            const float bias = sb1[oc];
            const int j0 = half * 7;
            #pragma unroll
            for (int jj = 0; jj < 7; ++jj) {
                float m = 0.f;
                #pragma unroll
                for (int dr = 0; dr < 2; ++dr)
                    #pragma unroll
                    for (int dc = 0; dc < 2; ++dc) {
                        float acc = bias;
                        #pragma unroll
                        for (int u = 0; u < 3; ++u)
                            #pragma unroll
                            for (int v = 0; v < 3; ++v)
                                acc = fmaf(X[dr + u][2 * jj + dc + v], W[u * 3 + v], acc);
                        m = fmaxf(m, acc);
                    }
                SF1F(oc, p + 1, j0 + jj + 1) = m;
            }
        }
    }
    __syncthreads();

    if (t < 112) {
        const int p = t >> 4, oc = t & 15;
        const float bias = sb2[oc];
        float acc[7][4];
        #pragma unroll
        for (int jj = 0; jj < 7; ++jj)
            #pragma unroll
            for (int s = 0; s < 4; ++s) acc[jj][s] = bias;
        for (int ic = 0; ic < 8; ++ic) {
            float X[4][16];
            #pragma unroll
            for (int u = 0; u < 4; ++u) {
                const float4* rp = reinterpret_cast<const float4*>(&SF1F(ic, 2 * p + u, 0));
                float4 a = rp[0], bb4 = rp[1], c4 = rp[2], d4 = rp[3];
                X[u][0] = a.x;  X[u][1] = a.y;  X[u][2] = a.z;  X[u][3] = a.w;
                X[u][4] = bb4.x; X[u][5] = bb4.y; X[u][6] = bb4.z; X[u][7] = bb4.w;
                X[u][8] = c4.x;  X[u][9] = c4.y;  X[u][10] = c4.z; X[u][11] = c4.w;
                X[u][12] = d4.x; X[u][13] = d4.y; X[u][14] = d4.z; X[u][15] = d4.w;
            }
            float W[9];
            #pragma unroll
            for (int k = 0; k < 9; ++k) W[k] = sw2p[oc * 76 + ic * 9 + k];
            #pragma unroll
            for (int jj = 0; jj < 7; ++jj)
                #pragma unroll
                for (int dr = 0; dr < 2; ++dr)
                    #pragma unroll
                    for (int dc = 0; dc < 2; ++dc)
                        #pragma unroll
                        for (int u = 0; u < 3; ++u)
                            #pragma unroll
                            for (int v = 0; v < 3; ++v)
                                acc[jj][dr * 2 + dc] =
                                    fmaf(X[dr + u][2 * jj + dc + v], W[u * 3 + v], acc[jj][dr * 2 + dc]);
        }
        #pragma unroll
        for (int jj = 0; jj < 7; ++jj) {
            float m = fmaxf(fmaxf(acc[jj][0], acc[jj][1]), fmaxf(acc[jj][2], acc[jj][3]));
            scomb[oc * 49 + p * 7 + jj] = fmaxf(m, 0.f);
        }
    }
    __syncthreads();

    if (t == 0) {
        scomb[786] = (sred[0] + sred[1] + sred[2] + sred[3]) * (1.f / 729.f);
        float f0 = scomb[0], f1 = scomb[1];
        float h[4];
        #pragma unroll
        for (int k = 0; k < 4; ++k)
            h[k] = tanhf(fmaf(f0, ssm[k * 2], fmaf(f1, ssm[k * 2 + 1], ssm[8 + k])));
        float l0 = ssm[20], l1 = ssm[21];
        #pragma unroll
        for (int k = 0; k < 4; ++k) {
            l0 = fmaf(h[k], ssm[12 + k], l0);
            l1 = fmaf(h[k], ssm[16 + k], l1);
        }
        float mx = fmaxf(l0, l1);
        float e0 = expf(l0 - mx), e1 = expf(l1 - mx);
        float inv = 1.f / (e0 + e1);
        scomb[784] = e0 * inv;
        scomb[785] = e1 * inv;
    }
    __syncthreads();

    {
        const int o = t & 63, w = t >> 6;
        const int k0 = w * 197;
        const int k1 = (w == 3) ? 787 : k0 + 197;
        const float* wp = wt + (size_t)k0 * 64 + o;
        float acc = 0.f;
        #pragma unroll 4
        for (int k = k0; k < k1; ++k) {
            acc = fmaf(scomb[k], *wp, acc);
            wp += 64;
        }
        sh1p[w][o] = acc;
    }
    __syncthreads();
    if (t < 64)
        sh1[t] = fmaxf(sh1p[0][t] + sh1p[1][t] + sh1p[2][t] + sh1p[3][t] + fc1b[t], 0.f);
    __syncthreads();

    {
        const int oo = t >> 6, lane = t & 63;
        float v = sh1[lane] * fc2w[oo * 64 + lane];
        #pragma unroll
        for (int off = 32; off > 0; off >>= 1)
            v += __shfl_xor(v, off, 64);
        if (lane == 0) pre[(size_t)b * 4 + oo] = v + fc2b[oo];
    }
}

__global__ __launch_bounds__(256) void k_bnstat_fb(const float* __restrict__ pre,
                                                   float* __restrict__ part)
{
    const int t = threadIdx.x;
    const int row = blockIdx.x * 256 + t;
    float4 v = reinterpret_cast<const float4*>(pre)[row];
    float s0 = v.x, s1 = v.y, s2 = v.z, s3 = v.w;
    float q0 = v.x * v.x, q1 = v.y * v.y, q2 = v.z * v.z, q3 = v.w * v.w;
    #pragma unroll
    for (int off = 32; off > 0; off >>= 1) {
        s0 += __shfl_xor(s0, off, 64);
        s1 += __shfl_xor(s1, off, 64);
        s2 += __shfl_xor(s2, off, 64);
        s3 += __shfl_xor(s3, off, 64);
        q0 += __shfl_xor(q0, off, 64);
        q1 += __shfl_xor(q1, off, 64);
        q2 += __shfl_xor(q2, off, 64);
        q3 += __shfl_xor(q3, off, 64);
    }
    __shared__ float acc[4][8];
    if ((t & 63) == 0) {
        int w = t >> 6;
        acc[w][0] = s0; acc[w][1] = s1; acc[w][2] = s2; acc[w][3] = s3;
        acc[w][4] = q0; acc[w][5] = q1; acc[w][6] = q2; acc[w][7] = q3;
    }
    __syncthreads();
    if (t < 8)
        part[blockIdx.x * 8 + t] = acc[0][t] + acc[1][t] + acc[2][t] + acc[3][t];
}

// ===========================================================================
extern "C" void kernel_launch(void* const* d_in, const int* in_sizes, int n_in,
                              void* d_out, int out_size, void* d_ws, size_t ws_size,
                              hipStream_t stream)
{
    const float* x    = (const float*)d_in[0];
    const float* w1   = (const float*)d_in[1];
    const float* b1   = (const float*)d_in[2];
    const float* w2   = (const float*)d_in[3];
    const float* b2   = (const float*)d_in[4];
    const float* s1w  = (const float*)d_in[5];
    const float* s1b  = (const float*)d_in[6];
    const float* s2w  = (const float*)d_in[7];
    const float* s2b  = (const float*)d_in[8];
    const float* fw   = (const float*)d_in[9];
    const float* fb   = (const float*)d_in[10];
    const float* fc1w = (const float*)d_in[11];
    const float* fc1b = (const float*)d_in[12];
    const float* fc2w = (const float*)d_in[13];
    const float* fc2b = (const float*)d_in[14];
    const float* bng  = (const float*)d_in[15];
    const float* bnb  = (const float*)d_in[16];

    float* out = (float*)d_out;

    const size_t COMB_BYTES = (size_t)NBATCH * 800 * 2;          // 26,214,400
    const size_t WT_BYTES   = 64 * 800 * 2;                      // 102,400
    const size_t NEED = COMB_BYTES + WT_BYTES + 256 * 8 * 4 + 32;

    if (ws_size >= NEED) {
        unsigned short* comb = (unsigned short*)d_ws;
        unsigned short* wtbf = (unsigned short*)((char*)d_ws + COMB_BYTES);
        float* part = (float*)((char*)d_ws + COMB_BYTES + WT_BYTES);
        float* ss   = part + 256 * 8;

        k_prep<<<200, 256, 0, stream>>>(fc1w, wtbf);
        k_conv<<<NBATCH, 256, 0, stream>>>(x, w1, b1, w2, b2, s1w, s1b, s2w, s2b,
                                           fw, fb, comb);
        k_fc<<<256, 256, 0, stream>>>(comb, wtbf, fc1b, fc2w, fc2b, out, part);
        k_bnfinal<<<1, 64, 0, stream>>>(part, bng, bnb, ss, 256);
        k_bnapply<<<64, 256, 0, stream>>>(ss, out);
    } else {
        float* part = (float*)d_ws;
        float* ss   = part + 512;
        float* wt   = ss + 8;

        k_transpose_fb<<<197, 256, 0, stream>>>(fc1w, wt);
        k_fused_fb<<<NBATCH, 256, 0, stream>>>(x, w1, b1, w2, b2, s1w, s1b, s2w, s2b,
                                               fw, fb, wt, fc1b, fc2w, fc2b, out);
        k_bnstat_fb<<<64, 256, 0, stream>>>(out, part);
        k_bnfinal<<<1, 64, 0, stream>>>(part, bng, bnb, ss, 64);
        k_bnapply<<<64, 256, 0, stream>>>(ss, out);
    }
}

// Round 4
// 276.559 us; speedup vs baseline: 2.6026x; 1.0006x over previous
//
#include <hip/hip_runtime.h>
#include <math.h>

#define NBATCH 16384
#define EPSV 1e-5f

typedef short short8 __attribute__((ext_vector_type(8)));
typedef float f32x4 __attribute__((ext_vector_type(4)));
union V8 { uint4 u; short8 s; };

__device__ __forceinline__ unsigned short f2bf(float f) {
    unsigned int x = __float_as_uint(f);
    return (unsigned short)((x + 0x7fffu + ((x >> 16) & 1u)) >> 16);  // RNE
}

// ---------------------------------------------------------------------------
// K0: fc1w [64][787] fp32 -> wt_bf16 [64][800] (K zero-padded)
// ---------------------------------------------------------------------------
__global__ __launch_bounds__(256) void k_prep(const float* __restrict__ fc1w,
                                              unsigned short* __restrict__ wt)
{
    int i = blockIdx.x * 256 + threadIdx.x;
    if (i < 64 * 800) {
        int n = i / 800, k = i - n * 800;
        float v = (k < 787) ? fc1w[n * 787 + k] : 0.f;
        wt[i] = f2bf(v);
    }
}

// ---------------------------------------------------------------------------
// K1: per-image conv1+conv2+filter+sampler -> combined bf16 [B][800] in ws
// ---------------------------------------------------------------------------
#define SF1I(ic, r, c) (((ic) * 16 + (r)) * 24 + (c))   // ushort index, row stride 24

__global__ __launch_bounds__(256) void k_conv(
    const float* __restrict__ x,
    const float* __restrict__ w1, const float* __restrict__ b1,
    const float* __restrict__ w2, const float* __restrict__ b2,
    const float* __restrict__ s1w, const float* __restrict__ s1b,
    const float* __restrict__ s2w, const float* __restrict__ s2b,
    const float* __restrict__ fw, const float* __restrict__ fb,
    unsigned short* __restrict__ comb)
{
    const int b = blockIdx.x;
    const int t = threadIdx.x;

    __shared__ float sxA[30][20];            // P cols 0..15 (zero-padded 30x30 input)
    __shared__ float sxB[30][20];            // P cols 14..29
    __shared__ unsigned short sf1[8 * 16 * 24];  // conv1 pooled out, bf16, stride 24
    __shared__ float scomb[800];
    __shared__ float sw1[72];
    __shared__ float sb1[8];
    __shared__ float sw2p[16 * 76];
    __shared__ float sb2[16];
    __shared__ float sred[4];
    __shared__ float ssm[27];                // s1w(8) s1b(4) s2w(8) s2b(2) fw(4) fb(1)

    // ---- zero tiles + stage small weights
    for (int i = t; i < 600; i += 256) { (&sxA[0][0])[i] = 0.f; (&sxB[0][0])[i] = 0.f; }
    {
        unsigned int* z = reinterpret_cast<unsigned int*>(sf1);
        for (int i = t; i < 8 * 16 * 12; i += 256) z[i] = 0u;
    }
    if (t < 16) scomb[784 + t] = 0.f;
    if (t < 72) sw1[t] = w1[t];
    if (t < 8) sb1[t] = b1[t];
    for (int i = t; i < 1152; i += 256) {
        int oc = i / 72, rem = i - oc * 72;
        sw2p[oc * 76 + rem] = w2[i];
    }
    if (t < 16) sb2[t] = b2[t];
    if (t < 8) ssm[t] = s1w[t];
    else if (t < 12) ssm[t] = s1b[t - 8];
    else if (t < 20) ssm[t] = s2w[t - 12];
    else if (t < 22) ssm[t] = s2b[t - 20];
    else if (t < 26) ssm[t] = fw[t - 22];
    else if (t == 26) ssm[t] = fb[0];
    __syncthreads();

    // ---- load x into both padded copies
    const float* xb = x + (size_t)b * 784;
    for (int i = t; i < 784; i += 256) {
        int r = i / 28, c = i - (i / 28) * 28;
        float v = xb[i];
        int pr = r + 1, pc = c + 1;
        if (pc <= 15) sxA[pr][pc] = v;
        if (pc >= 14) sxB[pr][pc - 14] = v;
    }
    __syncthreads();

    // ---- filter conv (2x2) + sigmoid partial sums
    {
        const float fw00 = ssm[22], fw01 = ssm[23], fw10 = ssm[24], fw11 = ssm[25];
        const float fbv = ssm[26];
        float fsum = 0.f;
        for (int i = t; i < 729; i += 256) {
            int r = i / 27, c = i - (i / 27) * 27;
            float x00, x01, x10, x11;
            if (c <= 13) {
                x00 = sxA[r + 1][c + 1]; x01 = sxA[r + 1][c + 2];
                x10 = sxA[r + 2][c + 1]; x11 = sxA[r + 2][c + 2];
            } else {
                int cb = c - 14;
                x00 = sxB[r + 1][cb + 1]; x01 = sxB[r + 1][cb + 2];
                x10 = sxB[r + 2][cb + 1]; x11 = sxB[r + 2][cb + 2];
            }
            float v = fbv;
            v = fmaf(x00, fw00, v); v = fmaf(x01, fw01, v);
            v = fmaf(x10, fw10, v); v = fmaf(x11, fw11, v);
            fsum += 1.f / (1.f + expf(-v));
        }
        #pragma unroll
        for (int off = 32; off > 0; off >>= 1)
            fsum += __shfl_xor(fsum, off, 64);
        if ((t & 63) == 0) sred[t >> 6] = fsum;
    }

    // ---- conv1 (1->8) + relu + maxpool -> sf1 bf16 (pooled 14x14, +1 pad)
    {
        const int half = t >> 7;
        const int id = t & 127;
        if (id < 112) {
            const int p = id >> 3, oc = id & 7;
            const float* base = half ? &sxB[0][0] : &sxA[0][0];
            float X[4][16];
            #pragma unroll
            for (int u = 0; u < 4; ++u) {
                const float4* rp = reinterpret_cast<const float4*>(base + (2 * p + u) * 20);
                float4 a = rp[0], bb4 = rp[1], c4 = rp[2], d4 = rp[3];
                X[u][0] = a.x;  X[u][1] = a.y;  X[u][2] = a.z;  X[u][3] = a.w;
                X[u][4] = bb4.x; X[u][5] = bb4.y; X[u][6] = bb4.z; X[u][7] = bb4.w;
                X[u][8] = c4.x;  X[u][9] = c4.y;  X[u][10] = c4.z; X[u][11] = c4.w;
                X[u][12] = d4.x; X[u][13] = d4.y; X[u][14] = d4.z; X[u][15] = d4.w;
            }
            float W[9];
            #pragma unroll
            for (int k = 0; k < 9; ++k) W[k] = sw1[oc * 9 + k];
            const float bias = sb1[oc];
            const int j0 = half * 7;
            #pragma unroll
            for (int jj = 0; jj < 7; ++jj) {
                float m = 0.f;
                #pragma unroll
                for (int dr = 0; dr < 2; ++dr)
                    #pragma unroll
                    for (int dc = 0; dc < 2; ++dc) {
                        float acc = bias;
                        #pragma unroll
                        for (int u = 0; u < 3; ++u)
                            #pragma unroll
                            for (int v = 0; v < 3; ++v)
                                acc = fmaf(X[dr + u][2 * jj + dc + v], W[u * 3 + v], acc);
                        m = fmaxf(m, acc);
                    }
                sf1[SF1I(oc, p + 1, j0 + jj + 1)] = f2bf(m);
            }
        }
    }
    __syncthreads();

    // ---- conv2 (8->16) + relu + maxpool -> scomb[0..783]
    if (t < 112) {
        const int p = t >> 4, oc = t & 15;
        const float bias = sb2[oc];
        float acc[7][4];
        #pragma unroll
        for (int jj = 0; jj < 7; ++jj)
            #pragma unroll
            for (int s = 0; s < 4; ++s) acc[jj][s] = bias;
        for (int ic = 0; ic < 8; ++ic) {
            float X[4][16];
            #pragma unroll
            for (int u = 0; u < 4; ++u) {
                const uint4* rp = reinterpret_cast<const uint4*>(&sf1[SF1I(ic, 2 * p + u, 0)]);
                uint4 q0 = rp[0], q1 = rp[1];
                X[u][0]  = __uint_as_float(q0.x << 16); X[u][1]  = __uint_as_float(q0.x & 0xffff0000u);
                X[u][2]  = __uint_as_float(q0.y << 16); X[u][3]  = __uint_as_float(q0.y & 0xffff0000u);
                X[u][4]  = __uint_as_float(q0.z << 16); X[u][5]  = __uint_as_float(q0.z & 0xffff0000u);
                X[u][6]  = __uint_as_float(q0.w << 16); X[u][7]  = __uint_as_float(q0.w & 0xffff0000u);
                X[u][8]  = __uint_as_float(q1.x << 16); X[u][9]  = __uint_as_float(q1.x & 0xffff0000u);
                X[u][10] = __uint_as_float(q1.y << 16); X[u][11] = __uint_as_float(q1.y & 0xffff0000u);
                X[u][12] = __uint_as_float(q1.z << 16); X[u][13] = __uint_as_float(q1.z & 0xffff0000u);
                X[u][14] = __uint_as_float(q1.w << 16); X[u][15] = __uint_as_float(q1.w & 0xffff0000u);
            }
            float W[9];
            #pragma unroll
            for (int k = 0; k < 9; ++k) W[k] = sw2p[oc * 76 + ic * 9 + k];
            #pragma unroll
            for (int jj = 0; jj < 7; ++jj)
                #pragma unroll
                for (int dr = 0; dr < 2; ++dr)
                    #pragma unroll
                    for (int dc = 0; dc < 2; ++dc)
                        #pragma unroll
                        for (int u = 0; u < 3; ++u)
                            #pragma unroll
                            for (int v = 0; v < 3; ++v)
                                acc[jj][dr * 2 + dc] =
                                    fmaf(X[dr + u][2 * jj + dc + v], W[u * 3 + v], acc[jj][dr * 2 + dc]);
        }
        #pragma unroll
        for (int jj = 0; jj < 7; ++jj) {
            float m = fmaxf(fmaxf(acc[jj][0], acc[jj][1]), fmaxf(acc[jj][2], acc[jj][3]));
            scomb[oc * 49 + p * 7 + jj] = fmaxf(m, 0.f);
        }
    }
    __syncthreads();

    // ---- sampler (thread 0) + filter mean finalize
    if (t == 0) {
        scomb[786] = (sred[0] + sred[1] + sred[2] + sred[3]) * (1.f / 729.f);
        float f0 = scomb[0], f1 = scomb[1];
        float h[4];
        #pragma unroll
        for (int k = 0; k < 4; ++k)
            h[k] = tanhf(fmaf(f0, ssm[k * 2], fmaf(f1, ssm[k * 2 + 1], ssm[8 + k])));
        float l0 = ssm[20], l1 = ssm[21];
        #pragma unroll
        for (int k = 0; k < 4; ++k) {
            l0 = fmaf(h[k], ssm[12 + k], l0);
            l1 = fmaf(h[k], ssm[16 + k], l1);
        }
        float mx = fmaxf(l0, l1);
        float e0 = expf(l0 - mx), e1 = expf(l1 - mx);
        float inv = 1.f / (e0 + e1);
        scomb[784] = e0 * inv;
        scomb[785] = e1 * inv;
    }
    __syncthreads();

    // ---- pack scomb -> combined bf16 row [800]
    if (t < 100) {
        const float4* sp = reinterpret_cast<const float4*>(scomb);
        float4 f0 = sp[2 * t], f1 = sp[2 * t + 1];
        uint4 o;
        o.x = (unsigned int)f2bf(f0.x) | ((unsigned int)f2bf(f0.y) << 16);
        o.y = (unsigned int)f2bf(f0.z) | ((unsigned int)f2bf(f0.w) << 16);
        o.z = (unsigned int)f2bf(f1.x) | ((unsigned int)f2bf(f1.y) << 16);
        o.w = (unsigned int)f2bf(f1.z) | ((unsigned int)f2bf(f1.w) << 16);
        reinterpret_cast<uint4*>(comb)[(size_t)b * 100 + t] = o;
    }
}

// ---------------------------------------------------------------------------
// K2: MFMA GEMM  h1 = relu(comb[16384,800] @ wt[64,800]^T + fc1b)
//     epilogue: out = h1 @ fc2w^T + fc2b  (+ per-block BN partial stats)
//     block = 64 rows, 4 waves (wave w: rows 16w..16w+15, all 64 cols)
// ---------------------------------------------------------------------------
__global__ __launch_bounds__(256) void k_fc(
    const unsigned short* __restrict__ A,   // [16384][800] bf16
    const unsigned short* __restrict__ Bw,  // [64][800] bf16
    const float* __restrict__ fc1b,
    const float* __restrict__ fc2w, const float* __restrict__ fc2b,
    float* __restrict__ out, float* __restrict__ part)
{
    __shared__ uint4 Asm[2][256];   // [buf][row*4 + kb_phys], kb_phys = kb ^ ((row>>1)&3)
    __shared__ uint4 Bsm[2][256];
    __shared__ float sh[64][68];
    __shared__ float sfc2[4][64];
    __shared__ float pacc[4][8];

    const int t = threadIdx.x;
    const int w = t >> 6, l = t & 63;
    const int blk = blockIdx.x;

    sfc2[t >> 6][t & 63] = fc2w[t];

    // staging map: row = t>>2, kb_phys = t&3 (contiguous LDS writes)
    const int srow = t >> 2, skbp = t & 3;
    const int skbl = skbp ^ ((srow >> 1) & 3);
    const uint4* Ag = reinterpret_cast<const uint4*>(A) + ((size_t)blk * 64 + srow) * 100;
    const uint4* Bg = reinterpret_cast<const uint4*>(Bw) + (size_t)srow * 100;
    const int sidx = srow * 4 + skbp;

    // read map (constant across k-steps)
    const int arow = w * 16 + (l & 15);
    const int aidx = arow * 4 + ((l >> 4) ^ ((arow >> 1) & 3));
    int bidx[4];
    #pragma unroll
    for (int nf = 0; nf < 4; ++nf) {
        int n = nf * 16 + (l & 15);
        bidx[nf] = n * 4 + ((l >> 4) ^ ((n >> 1) & 3));
    }

    f32x4 acc0 = {0.f, 0.f, 0.f, 0.f}, acc1 = acc0, acc2 = acc0, acc3 = acc0;

    // prologue: stage k-step 0
    Asm[0][sidx] = Ag[skbl];
    Bsm[0][sidx] = Bg[skbl];

    int buf = 0;
    for (int s = 0; s < 25; ++s) {
        __syncthreads();
        if (s < 24) {
            Asm[buf ^ 1][sidx] = Ag[(s + 1) * 4 + skbl];
            Bsm[buf ^ 1][sidx] = Bg[(s + 1) * 4 + skbl];
        }
        V8 av; av.u = Asm[buf][aidx];
        V8 b0; b0.u = Bsm[buf][bidx[0]];
        V8 b1; b1.u = Bsm[buf][bidx[1]];
        V8 b2; b2.u = Bsm[buf][bidx[2]];
        V8 b3; b3.u = Bsm[buf][bidx[3]];
        acc0 = __builtin_amdgcn_mfma_f32_16x16x32_bf16(av.s, b0.s, acc0, 0, 0, 0);
        acc1 = __builtin_amdgcn_mfma_f32_16x16x32_bf16(av.s, b1.s, acc1, 0, 0, 0);
        acc2 = __builtin_amdgcn_mfma_f32_16x16x32_bf16(av.s, b2.s, acc2, 0, 0, 0);
        acc3 = __builtin_amdgcn_mfma_f32_16x16x32_bf16(av.s, b3.s, acc3, 0, 0, 0);
        buf ^= 1;
    }

    // epilogue: relu(acc + fc1b) -> sh ;  C layout: row=(l>>4)*4+r, col=l&15
    {
        const int c0 = l & 15, r0 = w * 16 + (l >> 4) * 4;
        float fb0 = fc1b[c0], fb1 = fc1b[16 + c0], fb2 = fc1b[32 + c0], fb3 = fc1b[48 + c0];
        #pragma unroll
        for (int r = 0; r < 4; ++r) {
            sh[r0 + r][c0]      = fmaxf(acc0[r] + fb0, 0.f);
            sh[r0 + r][16 + c0] = fmaxf(acc1[r] + fb1, 0.f);
            sh[r0 + r][32 + c0] = fmaxf(acc2[r] + fb2, 0.f);
            sh[r0 + r][48 + c0] = fmaxf(acc3[r] + fb3, 0.f);
        }
    }
    __syncthreads();

    // fc2: t -> (row = t>>2, oo = t&3)
    {
        const int row = t >> 2, oo = t & 3;
        float s = fc2b[oo];
        #pragma unroll 8
        for (int o = 0; o < 64; ++o)
            s = fmaf(sh[row][o], sfc2[oo][o], s);
        out[((size_t)blk * 64 + row) * 4 + oo] = s;

        // BN partial stats: reduce over rows within wave (lanes with same oo)
        float rs = s, rq = s * s;
        #pragma unroll
        for (int off = 4; off < 64; off <<= 1) {
            rs += __shfl_xor(rs, off, 64);
            rq += __shfl_xor(rq, off, 64);
        }
        if (l < 4) pacc[w][l] = rs;
        else if (l < 8) pacc[w][l] = rq;
    }
    __syncthreads();
    if (t < 8)
        part[blk * 8 + t] = pacc[0][t] + pacc[1][t] + pacc[2][t] + pacc[3][t];
}

// ---------------------------------------------------------------------------
// BN finalize (nblocks partials) + apply
// ---------------------------------------------------------------------------
__global__ void k_bnfinal(const float* __restrict__ part,
                          const float* __restrict__ g, const float* __restrict__ bb,
                          float* __restrict__ ss, int nblocks)
{
    const int t = threadIdx.x;  // 64
    float s[8];
    #pragma unroll
    for (int i = 0; i < 8; ++i) s[i] = 0.f;
    for (int idx = t; idx < nblocks; idx += 64)
        #pragma unroll
        for (int i = 0; i < 8; ++i) s[i] += part[idx * 8 + i];
    #pragma unroll
    for (int i = 0; i < 8; ++i)
        #pragma unroll
        for (int off = 32; off > 0; off >>= 1)
            s[i] += __shfl_xor(s[i], off, 64);
    if (t == 0) {
        const float invB = 1.f / 16384.f;
        #pragma unroll
        for (int j = 0; j < 4; ++j) {
            float mu = s[j] * invB;
            float var = s[4 + j] * invB - mu * mu;
            float sc = g[j] * rsqrtf(var + EPSV);
            ss[j] = sc;
            ss[4 + j] = bb[j] - mu * sc;
        }
    }
}

__global__ __launch_bounds__(256) void k_bnapply(const float* __restrict__ ss,
                                                 float* __restrict__ out)
{
    const int row = blockIdx.x * 256 + threadIdx.x;
    float4 v = reinterpret_cast<float4*>(out)[row];
    v.x = fmaf(v.x, ss[0], ss[4]);
    v.y = fmaf(v.y, ss[1], ss[5]);
    v.z = fmaf(v.z, ss[2], ss[6]);
    v.w = fmaf(v.w, ss[3], ss[7]);
    reinterpret_cast<float4*>(out)[row] = v;
}

// ===========================================================================
// Fallback path (round-2 kernels) — used if ws_size is too small for comb
// ===========================================================================
__global__ __launch_bounds__(256) void k_transpose_fb(const float* __restrict__ in,
                                                      float* __restrict__ out)
{
    int i = blockIdx.x * 256 + threadIdx.x;
    if (i < 787 * 64) {
        int k = i >> 6, o = i & 63;
        out[i] = in[o * 787 + k];
    }
}

#define SF1F(ic, r, c) sf1[(ic) * 324 + (r) * 20 + (c)]

__global__ __launch_bounds__(256) void k_fused_fb(
    const float* __restrict__ x,
    const float* __restrict__ w1, const float* __restrict__ b1,
    const float* __restrict__ w2, const float* __restrict__ b2,
    const float* __restrict__ s1w, const float* __restrict__ s1b,
    const float* __restrict__ s2w, const float* __restrict__ s2b,
    const float* __restrict__ fw, const float* __restrict__ fb,
    const float* __restrict__ wt, const float* __restrict__ fc1b,
    const float* __restrict__ fc2w, const float* __restrict__ fc2b,
    float* __restrict__ pre)
{
    const int b = blockIdx.x;
    const int t = threadIdx.x;

    __shared__ float sxA[30][20];
    __shared__ float sxB[30][20];
    __shared__ float sf1[8 * 324];
    __shared__ float scomb[788];
    __shared__ float sw1[72];
    __shared__ float sb1[8];
    __shared__ float sw2p[16 * 76];
    __shared__ float sb2[16];
    __shared__ float sh1p[4][64];
    __shared__ float sh1[64];
    __shared__ float sred[4];
    __shared__ float ssm[27];

    for (int i = t; i < 600; i += 256) { (&sxA[0][0])[i] = 0.f; (&sxB[0][0])[i] = 0.f; }
    for (int i = t; i < 8 * 324; i += 256) sf1[i] = 0.f;
    if (t < 72) sw1[t] = w1[t];
    if (t < 8) sb1[t] = b1[t];
    for (int i = t; i < 1152; i += 256) {
        int oc = i / 72, rem = i - oc * 72;
        sw2p[oc * 76 + rem] = w2[i];
    }
    if (t < 16) sb2[t] = b2[t];
    if (t < 8) ssm[t] = s1w[t];
    else if (t < 12) ssm[t] = s1b[t - 8];
    else if (t < 20) ssm[t] = s2w[t - 12];
    else if (t < 22) ssm[t] = s2b[t - 20];
    else if (t < 26) ssm[t] = fw[t - 22];
    else if (t == 26) ssm[t] = fb[0];
    __syncthreads();

    const float* xb = x + (size_t)b * 784;
    for (int i = t; i < 784; i += 256) {
        int r = i / 28, c = i - (i / 28) * 28;
        float v = xb[i];
        int pr = r + 1, pc = c + 1;
        if (pc <= 15) sxA[pr][pc] = v;
        if (pc >= 14) sxB[pr][pc - 14] = v;
    }
    __syncthreads();

    {
        const float fw00 = ssm[22], fw01 = ssm[23], fw10 = ssm[24], fw11 = ssm[25];
        const float fbv = ssm[26];
        float fsum = 0.f;
        for (int i = t; i < 729; i += 256) {
            int r = i / 27, c = i - (i / 27) * 27;
            float x00, x01, x10, x11;
            if (c <= 13) {
                x00 = sxA[r + 1][c + 1]; x01 = sxA[r + 1][c + 2];
                x10 = sxA[r + 2][c + 1]; x11 = sxA[r + 2][c + 2];
            } else {
                int cb = c - 14;
                x00 = sxB[r + 1][cb + 1]; x01 = sxB[r + 1][cb + 2];
                x10 = sxB[r + 2][cb + 1]; x11 = sxB[r + 2][cb + 2];
            }
            float v = fbv;
            v = fmaf(x00, fw00, v); v = fmaf(x01, fw01, v);
            v = fmaf(x10, fw10, v); v = fmaf(x11, fw11, v);
            fsum += 1.f / (1.f + expf(-v));
        }
        #pragma unroll
        for (int off = 32; off > 0; off >>= 1)
            fsum += __shfl_xor(fsum, off, 64);
        if ((t & 63) == 0) sred[t >> 6] = fsum;
    }

    {
        const int half = t >> 7;
        const int id = t & 127;
        if (id < 112) {
            const int p = id >> 3, oc = id & 7;
            const float* base = half ? &sxB[0][0] : &sxA[0][0];
            float X[4][16];
            #pragma unroll
            for (int u = 0; u < 4; ++u) {
                const float4* rp = reinterpret_cast<const float4*>(base + (2 * p + u) * 20);
                float4 a = rp[0], bb4 = rp[1], c4 = rp[2], d4 = rp[3];
                X[u][0] = a.x;  X[u][1] = a.y;  X[u][2] = a.z;  X[u][3] = a.w;
                X[u][4] = bb4.x; X[u][5] = bb4.y; X[u][6] = bb4.z; X[u][7] = bb4.w;
                X[u][8] = c4.x;  X[u][9] = c4.y;  X[u][10] = c4.z; X[u][11] = c4.w;
                X[u][12] = d4.x; X[u][13] = d4.y; X[u][14] = d4.z; X[u][15] = d4.w;
            }
            float W[9];
            #pragma unroll
            for (int k = 0; k < 9; ++k) W[k] = sw1[oc * 9 + k];
            const float bias = sb1[oc];
            const int j0 = half * 7;
            #pragma unroll
            for (int jj = 0; jj < 7; ++jj) {
                float m = 0.f;
                #pragma unroll
                for (int dr = 0; dr < 2; ++dr)
                    #pragma unroll
                    for (int dc = 0; dc < 2; ++dc) {
                        float acc = bias;
                        #pragma unroll
                        for (int u = 0; u < 3; ++u)
                            #pragma unroll
                            for (int v = 0; v < 3; ++v)
                                acc = fmaf(X[dr + u][2 * jj + dc + v], W[u * 3 + v], acc);
                        m = fmaxf(m, acc);
                    }
                SF1F(oc, p + 1, j0 + jj + 1) = m;
            }
        }
    }
    __syncthreads();

    if (t < 112) {
        const int p = t >> 4, oc = t & 15;
        const float bias = sb2[oc];
        float acc[7][4];
        #pragma unroll
        for (int jj = 0; jj < 7; ++jj)
            #pragma unroll
            for (int s = 0; s < 4; ++s) acc[jj][s] = bias;
        for (int ic = 0; ic < 8; ++ic) {
            float X[4][16];
            #pragma unroll
            for (int u = 0; u < 4; ++u) {
                const float4* rp = reinterpret_cast<const float4*>(&SF1F(ic, 2 * p + u, 0));
                float4 a = rp[0], bb4 = rp[1], c4 = rp[2], d4 = rp[3];
                X[u][0] = a.x;  X[u][1] = a.y;  X[u][2] = a.z;  X[u][3] = a.w;
                X[u][4] = bb4.x; X[u][5] = bb4.y; X[u][6] = bb4.z; X[u][7] = bb4.w;
                X[u][8] = c4.x;  X[u][9] = c4.y;  X[u][10] = c4.z; X[u][11] = c4.w;
                X[u][12] = d4.x; X[u][13] = d4.y; X[u][14] = d4.z; X[u][15] = d4.w;
            }
            float W[9];
            #pragma unroll
            for (int k = 0; k < 9; ++k) W[k] = sw2p[oc * 76 + ic * 9 + k];
            #pragma unroll
            for (int jj = 0; jj < 7; ++jj)
                #pragma unroll
                for (int dr = 0; dr < 2; ++dr)
                    #pragma unroll
                    for (int dc = 0; dc < 2; ++dc)
                        #pragma unroll
                        for (int u = 0; u < 3; ++u)
                            #pragma unroll
                            for (int v = 0; v < 3; ++v)
                                acc[jj][dr * 2 + dc] =
                                    fmaf(X[dr + u][2 * jj + dc + v], W[u * 3 + v], acc[jj][dr * 2 + dc]);
        }
        #pragma unroll
        for (int jj = 0; jj < 7; ++jj) {
            float m = fmaxf(fmaxf(acc[jj][0], acc[jj][1]), fmaxf(acc[jj][2], acc[jj][3]));
            scomb[oc * 49 + p * 7 + jj] = fmaxf(m, 0.f);
        }
    }
    __syncthreads();

    if (t == 0) {
        scomb[786] = (sred[0] + sred[1] + sred[2] + sred[3]) * (1.f / 729.f);
        float f0 = scomb[0], f1 = scomb[1];
        float h[4];
        #pragma unroll
        for (int k = 0; k < 4; ++k)
            h[k] = tanhf(fmaf(f0, ssm[k * 2], fmaf(f1, ssm[k * 2 + 1], ssm[8 + k])));
        float l0 = ssm[20], l1 = ssm[21];
        #pragma unroll
        for (int k = 0; k < 4; ++k) {
            l0 = fmaf(h[k], ssm[12 + k], l0);
            l1 = fmaf(h[k], ssm[16 + k], l1);
        }
        float mx = fmaxf(l0, l1);
        float e0 = expf(l0 - mx), e1 = expf(l1 - mx);
        float inv = 1.f / (e0 + e1);
        scomb[784] = e0 * inv;
        scomb[785] = e1 * inv;
    }
    __syncthreads();

    {
        const int o = t & 63, w = t >> 6;
        const int k0 = w * 197;
        const int k1 = (w == 3) ? 787 : k0 + 197;
        const float* wp = wt + (size_t)k0 * 64 + o;
        float acc = 0.f;
        #pragma unroll 4
        for (int k = k0; k < k1; ++k) {
            acc = fmaf(scomb[k], *wp, acc);
            wp += 64;
        }
        sh1p[w][o] = acc;
    }
    __syncthreads();
    if (t < 64)
        sh1[t] = fmaxf(sh1p[0][t] + sh1p[1][t] + sh1p[2][t] + sh1p[3][t] + fc1b[t], 0.f);
    __syncthreads();

    {
        const int oo = t >> 6, lane = t & 63;
        float v = sh1[lane] * fc2w[oo * 64 + lane];
        #pragma unroll
        for (int off = 32; off > 0; off >>= 1)
            v += __shfl_xor(v, off, 64);
        if (lane == 0) pre[(size_t)b * 4 + oo] = v + fc2b[oo];
    }
}

__global__ __launch_bounds__(256) void k_bnstat_fb(const float* __restrict__ pre,
                                                   float* __restrict__ part)
{
    const int t = threadIdx.x;
    const int row = blockIdx.x * 256 + t;
    float4 v = reinterpret_cast<const float4*>(pre)[row];
    float s0 = v.x, s1 = v.y, s2 = v.z, s3 = v.w;
    float q0 = v.x * v.x, q1 = v.y * v.y, q2 = v.z * v.z, q3 = v.w * v.w;
    #pragma unroll
    for (int off = 32; off > 0; off >>= 1) {
        s0 += __shfl_xor(s0, off, 64);
        s1 += __shfl_xor(s1, off, 64);
        s2 += __shfl_xor(s2, off, 64);
        s3 += __shfl_xor(s3, off, 64);
        q0 += __shfl_xor(q0, off, 64);
        q1 += __shfl_xor(q1, off, 64);
        q2 += __shfl_xor(q2, off, 64);
        q3 += __shfl_xor(q3, off, 64);
    }
    __shared__ float acc[4][8];
    if ((t & 63) == 0) {
        int w = t >> 6;
        acc[w][0] = s0; acc[w][1] = s1; acc[w][2] = s2; acc[w][3] = s3;
        acc[w][4] = q0; acc[w][5] = q1; acc[w][6] = q2; acc[w][7] = q3;
    }
    __syncthreads();
    if (t < 8)
        part[blockIdx.x * 8 + t] = acc[0][t] + acc[1][t] + acc[2][t] + acc[3][t];
}

// ===========================================================================
extern "C" void kernel_launch(void* const* d_in, const int* in_sizes, int n_in,
                              void* d_out, int out_size, void* d_ws, size_t ws_size,
                              hipStream_t stream)
{
    const float* x    = (const float*)d_in[0];
    const float* w1   = (const float*)d_in[1];
    const float* b1   = (const float*)d_in[2];
    const float* w2   = (const float*)d_in[3];
    const float* b2   = (const float*)d_in[4];
    const float* s1w  = (const float*)d_in[5];
    const float* s1b  = (const float*)d_in[6];
    const float* s2w  = (const float*)d_in[7];
    const float* s2b  = (const float*)d_in[8];
    const float* fw   = (const float*)d_in[9];
    const float* fb   = (const float*)d_in[10];
    const float* fc1w = (const float*)d_in[11];
    const float* fc1b = (const float*)d_in[12];
    const float* fc2w = (const float*)d_in[13];
    const float* fc2b = (const float*)d_in[14];
    const float* bng  = (const float*)d_in[15];
    const float* bnb  = (const float*)d_in[16];

    float* out = (float*)d_out;

    const size_t COMB_BYTES = (size_t)NBATCH * 800 * 2;          // 26,214,400
    const size_t WT_BYTES   = 64 * 800 * 2;                      // 102,400
    const size_t NEED = COMB_BYTES + WT_BYTES + 256 * 8 * 4 + 32;

    if (ws_size >= NEED) {
        unsigned short* comb = (unsigned short*)d_ws;
        unsigned short* wtbf = (unsigned short*)((char*)d_ws + COMB_BYTES);
        float* part = (float*)((char*)d_ws + COMB_BYTES + WT_BYTES);
        float* ss   = part + 256 * 8;

        k_prep<<<200, 256, 0, stream>>>(fc1w, wtbf);
        k_conv<<<NBATCH, 256, 0, stream>>>(x, w1, b1, w2, b2, s1w, s1b, s2w, s2b,
                                           fw, fb, comb);
        k_fc<<<256, 256, 0, stream>>>(comb, wtbf, fc1b, fc2w, fc2b, out, part);
        k_bnfinal<<<1, 64, 0, stream>>>(part, bng, bnb, ss, 256);
        k_bnapply<<<64, 256, 0, stream>>>(ss, out);
    } else {
        float* part = (float*)d_ws;
        float* ss   = part + 512;
        float* wt   = ss + 8;

        k_transpose_fb<<<197, 256, 0, stream>>>(fc1w, wt);
        k_fused_fb<<<NBATCH, 256, 0, stream>>>(x, w1, b1, w2, b2, s1w, s1b, s2w, s2b,
                                               fw, fb, wt, fc1b, fc2w, fc2b, out);
        k_bnstat_fb<<<64, 256, 0, stream>>>(out, part);
        k_bnfinal<<<1, 64, 0, stream>>>(part, bng, bnb, ss, 64);
        k_bnapply<<<64, 256, 0, stream>>>(ss, out);
    }
}

// Round 5
// 115.999 us; speedup vs baseline: 6.2050x; 2.3841x over previous
//
#include <hip/hip_runtime.h>
#include <math.h>

#define NBATCH 16384
#define EPSV 1e-5f

typedef short short8 __attribute__((ext_vector_type(8)));
typedef float f32x4 __attribute__((ext_vector_type(4)));
union V8 { uint4 u; short8 s; };

__device__ __forceinline__ unsigned short f2bf(float f) {
    unsigned int x = __float_as_uint(f);
    return (unsigned short)((x + 0x7fffu + ((x >> 16) & 1u)) >> 16);  // RNE
}

// ---------------------------------------------------------------------------
// K0: fc1w [64][787] fp32 -> wt_bf16 [64][800] (K zero-padded)
// ---------------------------------------------------------------------------
__global__ __launch_bounds__(256) void k_prep(const float* __restrict__ fc1w,
                                              unsigned short* __restrict__ wt)
{
    int i = blockIdx.x * 256 + threadIdx.x;
    if (i < 64 * 800) {
        int n = i / 800, k = i - n * 800;
        float v = (k < 787) ? fc1w[n * 787 + k] : 0.f;
        wt[i] = f2bf(v);
    }
}

// ---------------------------------------------------------------------------
// K1: per-image conv1 (VALU) + conv2 (MFMA, channels-last) + filter + sampler
//     -> combined bf16 [B][800] in ws.  One 256-thread block per image.
// ---------------------------------------------------------------------------
#define SX(r, c) sx[(r) * 36 + (c)]   // padded 30x30 input, row stride 36 (16B-aligned rows, bank-spread 4/row)

__global__ __launch_bounds__(256) void k_conv(
    const float* __restrict__ x,
    const float* __restrict__ w1, const float* __restrict__ b1,
    const float* __restrict__ w2, const float* __restrict__ b2,
    const float* __restrict__ s1w, const float* __restrict__ s1b,
    const float* __restrict__ s2w, const float* __restrict__ s2b,
    const float* __restrict__ fw, const float* __restrict__ fb,
    unsigned short* __restrict__ comb)
{
    const int b = blockIdx.x;
    const int t = threadIdx.x;

    __shared__ __align__(16) float sx[30 * 36];
    // conv1 pooled out, channels-last: cell (R,C) = 8 bf16 (one uint4), row stride 136 ush (272B, 16B-aligned)
    __shared__ __align__(16) unsigned short sf1[16 * 136];
    // W2 as MFMA-A: [12 uv-slots][16 oc][8 ic] bf16 (slots 9..11 zero)
    __shared__ __align__(16) unsigned short A_lds[12 * 16 * 8];
    __shared__ __align__(16) float scomb[800];
    __shared__ float sred[4];
    __shared__ float ssm[27];       // s1w(8) s1b(4) s2w(8) s2b(2) fw(4) fb(1)
    __shared__ float sb2s[16];

    // ================= phase A: zeros + weight prep + x staging =============
    // sx pad ring (row 0, row 29, col 0, col 29)
    if (t < 116) {
        int r, c;
        if (t < 30)      { r = 0;      c = t; }
        else if (t < 60) { r = 29;     c = t - 30; }
        else if (t < 88) { r = t - 59; c = 0; }      // rows 1..28
        else             { r = t - 87; c = 29; }     // rows 1..28
        SX(r, c) = 0.f;
    }
    // sf1 pad ring: 60 cells, one uint4 each
    if (t < 60) {
        int R, C;
        if (t < 16)      { R = 0;      C = t; }
        else if (t < 32) { R = 15;     C = t - 16; }
        else if (t < 46) { R = t - 31; C = 0; }      // rows 1..14
        else             { R = t - 45; C = 15; }     // rows 1..14
        *reinterpret_cast<uint4*>(&sf1[R * 136 + C * 8]) = uint4{0u, 0u, 0u, 0u};
    }
    // scomb tail zeros (787..799 stay 0; 784..786 overwritten by sampler)
    if (t >= 60 && t < 76) scomb[784 + (t - 60)] = 0.f;
    // small-weight staging
    if (t >= 128 && t < 136) ssm[t - 128] = s1w[t - 128];
    else if (t >= 136 && t < 140) ssm[t - 128] = s1b[t - 136];
    else if (t >= 140 && t < 148) ssm[t - 128] = s2w[t - 140];
    else if (t >= 148 && t < 150) ssm[t - 128] = s2b[t - 148];
    else if (t >= 150 && t < 154) ssm[t - 128] = fw[t - 150];
    else if (t == 154) ssm[26] = fb[0];
    if (t >= 160 && t < 176) sb2s[t - 160] = b2[t - 160];
    // W2 -> A_lds (bf16, uv-major)
    for (int idx = t; idx < 1152; idx += 256) {
        int oc = idx / 72, rem = idx - oc * 72;
        int ic = rem / 9, uv = rem - ic * 9;
        A_lds[(uv * 16 + oc) * 8 + ic] = f2bf(w2[idx]);
    }
    if (t < 48) *reinterpret_cast<uint4*>(&A_lds[1152 + t * 8]) = uint4{0u, 0u, 0u, 0u};
    // x -> sx interior
    {
        const float* xb = x + (size_t)b * 784;
        for (int i = t; i < 784; i += 256) {
            int r = i / 28, c = i - (i / 28) * 28;
            SX(r + 1, c + 1) = xb[i];
        }
    }
    __syncthreads();

    // ================= phase B: filter conv + conv1 =========================
    // filter conv (2x2) + sigmoid partial sums
    {
        const float fw00 = ssm[22], fw01 = ssm[23], fw10 = ssm[24], fw11 = ssm[25];
        const float fbv = ssm[26];
        float fsum = 0.f;
        for (int i = t; i < 729; i += 256) {
            int r = i / 27, c = i - (i / 27) * 27;
            float v = fbv;
            v = fmaf(SX(r + 1, c + 1), fw00, v);
            v = fmaf(SX(r + 1, c + 2), fw01, v);
            v = fmaf(SX(r + 2, c + 1), fw10, v);
            v = fmaf(SX(r + 2, c + 2), fw11, v);
            fsum += __frcp_rn(1.f + __expf(-v));
        }
        #pragma unroll
        for (int off = 32; off > 0; off >>= 1)
            fsum += __shfl_xor(fsum, off, 64);
        if ((t & 63) == 0) sred[t >> 6] = fsum;
    }

    // conv1: thread (p,j) computes all 8 oc of pooled cell (p,j); 196 threads
    if (t < 196) {
        const int p = t / 14, j = t - (t / 14) * 14;
        float X[4][4];
        #pragma unroll
        for (int u = 0; u < 4; ++u) {
            float2 a = *reinterpret_cast<const float2*>(&SX(2 * p + u, 2 * j));
            float2 c2 = *reinterpret_cast<const float2*>(&SX(2 * p + u, 2 * j + 2));
            X[u][0] = a.x; X[u][1] = a.y; X[u][2] = c2.x; X[u][3] = c2.y;
        }
        unsigned short outv[8];
        #pragma unroll
        for (int h = 0; h < 2; ++h) {          // 2 passes of 4 oc (reg pressure)
            float acc[4][4];
            #pragma unroll
            for (int o = 0; o < 4; ++o) {
                const float bias = b1[h * 4 + o];     // uniform -> s-load
                #pragma unroll
                for (int s = 0; s < 4; ++s) acc[o][s] = bias;
            }
            #pragma unroll
            for (int o = 0; o < 4; ++o)
                #pragma unroll
                for (int u = 0; u < 3; ++u)
                    #pragma unroll
                    for (int v = 0; v < 3; ++v) {
                        const float wv = w1[(h * 4 + o) * 9 + u * 3 + v];  // uniform -> s-load
                        acc[o][0] = fmaf(X[u][v],         wv, acc[o][0]);
                        acc[o][1] = fmaf(X[u][v + 1],     wv, acc[o][1]);
                        acc[o][2] = fmaf(X[u + 1][v],     wv, acc[o][2]);
                        acc[o][3] = fmaf(X[u + 1][v + 1], wv, acc[o][3]);
                    }
            #pragma unroll
            for (int o = 0; o < 4; ++o) {
                float m = fmaxf(fmaxf(acc[o][0], acc[o][1]), fmaxf(acc[o][2], acc[o][3]));
                outv[h * 4 + o] = f2bf(fmaxf(m, 0.f));
            }
        }
        *reinterpret_cast<uint4*>(&sf1[(p + 1) * 136 + (j + 1) * 8]) =
            *reinterpret_cast<const uint4*>(outv);
    }
    __syncthreads();

    // ================= phase C: conv2 via MFMA ==============================
    // D[16 oc][16 pos] per mfma; pos-tile = (dr in 0..1) x (q in 0..7, 7 used);
    // two tiles (dc=0,1) per pooled row pp; pool = reg-max + shfl_xor(8).
    {
        const int l = t & 63, w = t >> 6;
        const int n = l & 15, g = l >> 4;
        const int qr = n & 7;
        const int q = (qr < 7) ? qr : 6;       // clamp dead lane
        const int dr = n >> 3;

        int offs[3];
        V8 af[3];
        #pragma unroll
        for (int s = 0; s < 3; ++s) {
            const int slot = s * 4 + g;
            const int u = slot / 3, v = slot - 3 * (slot / 3);
            offs[s] = (slot <= 8) ? (u * 136 + v * 8) : 0;
            af[s].u = *reinterpret_cast<const uint4*>(&A_lds[(slot * 16 + n) * 8]);
        }

        for (int pp = w; pp < 7; pp += 4) {
            const int rbase = (2 * pp + dr) * 136 + (2 * q) * 8;
            f32x4 acc0 = {0.f, 0.f, 0.f, 0.f}, acc1 = {0.f, 0.f, 0.f, 0.f};
            #pragma unroll
            for (int s = 0; s < 3; ++s) {
                V8 b0, b1v;
                b0.u  = *reinterpret_cast<const uint4*>(&sf1[rbase + offs[s]]);
                b1v.u = *reinterpret_cast<const uint4*>(&sf1[rbase + 8 + offs[s]]);
                acc0 = __builtin_amdgcn_mfma_f32_16x16x32_bf16(af[s].s, b0.s, acc0, 0, 0, 0);
                acc1 = __builtin_amdgcn_mfma_f32_16x16x32_bf16(af[s].s, b1v.s, acc1, 0, 0, 0);
            }
            #pragma unroll
            for (int i = 0; i < 4; ++i) {
                const float bias = sb2s[4 * g + i];
                float m = fmaxf(acc0[i], acc1[i]);            // max over dc
                m = fmaxf(m, __shfl_xor(m, 8, 64));           // max over dr
                if (n < 7)                                    // dr==0 && q valid
                    scomb[(4 * g + i) * 49 + pp * 7 + q] = fmaxf(m + bias, 0.f);
            }
        }
    }
    __syncthreads();

    // ================= phase D: sampler + filter-mean finalize ==============
    if (t == 0) {
        scomb[786] = (sred[0] + sred[1] + sred[2] + sred[3]) * (1.f / 729.f);
        float f0 = scomb[0], f1 = scomb[1];
        float h[4];
        #pragma unroll
        for (int k = 0; k < 4; ++k)
            h[k] = tanhf(fmaf(f0, ssm[k * 2], fmaf(f1, ssm[k * 2 + 1], ssm[8 + k])));
        float l0 = ssm[20], l1 = ssm[21];
        #pragma unroll
        for (int k = 0; k < 4; ++k) {
            l0 = fmaf(h[k], ssm[12 + k], l0);
            l1 = fmaf(h[k], ssm[16 + k], l1);
        }
        float mx = fmaxf(l0, l1);
        float e0 = __expf(l0 - mx), e1 = __expf(l1 - mx);
        float inv = 1.f / (e0 + e1);
        scomb[784] = e0 * inv;
        scomb[785] = e1 * inv;
    }
    __syncthreads();

    // ================= phase E: pack scomb -> combined bf16 row [800] =======
    if (t < 100) {
        const float4* sp = reinterpret_cast<const float4*>(scomb);
        float4 f0 = sp[2 * t], f1 = sp[2 * t + 1];
        uint4 o;
        o.x = (unsigned int)f2bf(f0.x) | ((unsigned int)f2bf(f0.y) << 16);
        o.y = (unsigned int)f2bf(f0.z) | ((unsigned int)f2bf(f0.w) << 16);
        o.z = (unsigned int)f2bf(f1.x) | ((unsigned int)f2bf(f1.y) << 16);
        o.w = (unsigned int)f2bf(f1.z) | ((unsigned int)f2bf(f1.w) << 16);
        reinterpret_cast<uint4*>(comb)[(size_t)b * 100 + t] = o;
    }
}

// ---------------------------------------------------------------------------
// K2: MFMA GEMM  h1 = relu(comb[16384,800] @ wt[64,800]^T + fc1b)
//     epilogue: out = h1 @ fc2w^T + fc2b  (+ per-block BN partial stats)
// ---------------------------------------------------------------------------
__global__ __launch_bounds__(256) void k_fc(
    const unsigned short* __restrict__ A,   // [16384][800] bf16
    const unsigned short* __restrict__ Bw,  // [64][800] bf16
    const float* __restrict__ fc1b,
    const float* __restrict__ fc2w, const float* __restrict__ fc2b,
    float* __restrict__ out, float* __restrict__ part)
{
    __shared__ uint4 Asm[2][256];   // [buf][row*4 + kb_phys], kb_phys = kb ^ ((row>>1)&3)
    __shared__ uint4 Bsm[2][256];
    __shared__ float sh[64][68];
    __shared__ float sfc2[4][64];
    __shared__ float pacc[4][8];

    const int t = threadIdx.x;
    const int w = t >> 6, l = t & 63;
    const int blk = blockIdx.x;

    sfc2[t >> 6][t & 63] = fc2w[t];

    const int srow = t >> 2, skbp = t & 3;
    const int skbl = skbp ^ ((srow >> 1) & 3);
    const uint4* Ag = reinterpret_cast<const uint4*>(A) + ((size_t)blk * 64 + srow) * 100;
    const uint4* Bg = reinterpret_cast<const uint4*>(Bw) + (size_t)srow * 100;
    const int sidx = srow * 4 + skbp;

    const int arow = w * 16 + (l & 15);
    const int aidx = arow * 4 + ((l >> 4) ^ ((arow >> 1) & 3));
    int bidx[4];
    #pragma unroll
    for (int nf = 0; nf < 4; ++nf) {
        int n = nf * 16 + (l & 15);
        bidx[nf] = n * 4 + ((l >> 4) ^ ((n >> 1) & 3));
    }

    f32x4 acc0 = {0.f, 0.f, 0.f, 0.f}, acc1 = acc0, acc2 = acc0, acc3 = acc0;

    Asm[0][sidx] = Ag[skbl];
    Bsm[0][sidx] = Bg[skbl];

    int buf = 0;
    for (int s = 0; s < 25; ++s) {
        __syncthreads();
        if (s < 24) {
            Asm[buf ^ 1][sidx] = Ag[(s + 1) * 4 + skbl];
            Bsm[buf ^ 1][sidx] = Bg[(s + 1) * 4 + skbl];
        }
        V8 av; av.u = Asm[buf][aidx];
        V8 b0; b0.u = Bsm[buf][bidx[0]];
        V8 b1; b1.u = Bsm[buf][bidx[1]];
        V8 b2; b2.u = Bsm[buf][bidx[2]];
        V8 b3; b3.u = Bsm[buf][bidx[3]];
        acc0 = __builtin_amdgcn_mfma_f32_16x16x32_bf16(av.s, b0.s, acc0, 0, 0, 0);
        acc1 = __builtin_amdgcn_mfma_f32_16x16x32_bf16(av.s, b1.s, acc1, 0, 0, 0);
        acc2 = __builtin_amdgcn_mfma_f32_16x16x32_bf16(av.s, b2.s, acc2, 0, 0, 0);
        acc3 = __builtin_amdgcn_mfma_f32_16x16x32_bf16(av.s, b3.s, acc3, 0, 0, 0);
        buf ^= 1;
    }

    {
        const int c0 = l & 15, r0 = w * 16 + (l >> 4) * 4;
        float fb0 = fc1b[c0], fb1 = fc1b[16 + c0], fb2 = fc1b[32 + c0], fb3 = fc1b[48 + c0];
        #pragma unroll
        for (int r = 0; r < 4; ++r) {
            sh[r0 + r][c0]      = fmaxf(acc0[r] + fb0, 0.f);
            sh[r0 + r][16 + c0] = fmaxf(acc1[r] + fb1, 0.f);
            sh[r0 + r][32 + c0] = fmaxf(acc2[r] + fb2, 0.f);
            sh[r0 + r][48 + c0] = fmaxf(acc3[r] + fb3, 0.f);
        }
    }
    __syncthreads();

    {
        const int row = t >> 2, oo = t & 3;
        float s = fc2b[oo];
        #pragma unroll 8
        for (int o = 0; o < 64; ++o)
            s = fmaf(sh[row][o], sfc2[oo][o], s);
        out[((size_t)blk * 64 + row) * 4 + oo] = s;

        float rs = s, rq = s * s;
        #pragma unroll
        for (int off = 4; off < 64; off <<= 1) {
            rs += __shfl_xor(rs, off, 64);
            rq += __shfl_xor(rq, off, 64);
        }
        if (l < 4) pacc[w][l] = rs;
        else if (l < 8) pacc[w][l] = rq;
    }
    __syncthreads();
    if (t < 8)
        part[blk * 8 + t] = pacc[0][t] + pacc[1][t] + pacc[2][t] + pacc[3][t];
}

// ---------------------------------------------------------------------------
// BN finalize + apply
// ---------------------------------------------------------------------------
__global__ void k_bnfinal(const float* __restrict__ part,
                          const float* __restrict__ g, const float* __restrict__ bb,
                          float* __restrict__ ss, int nblocks)
{
    const int t = threadIdx.x;  // 64
    float s[8];
    #pragma unroll
    for (int i = 0; i < 8; ++i) s[i] = 0.f;
    for (int idx = t; idx < nblocks; idx += 64)
        #pragma unroll
        for (int i = 0; i < 8; ++i) s[i] += part[idx * 8 + i];
    #pragma unroll
    for (int i = 0; i < 8; ++i)
        #pragma unroll
        for (int off = 32; off > 0; off >>= 1)
            s[i] += __shfl_xor(s[i], off, 64);
    if (t == 0) {
        const float invB = 1.f / 16384.f;
        #pragma unroll
        for (int j = 0; j < 4; ++j) {
            float mu = s[j] * invB;
            float var = s[4 + j] * invB - mu * mu;
            float sc = g[j] * rsqrtf(var + EPSV);
            ss[j] = sc;
            ss[4 + j] = bb[j] - mu * sc;
        }
    }
}

__global__ __launch_bounds__(256) void k_bnapply(const float* __restrict__ ss,
                                                 float* __restrict__ out)
{
    const int row = blockIdx.x * 256 + threadIdx.x;
    float4 v = reinterpret_cast<float4*>(out)[row];
    v.x = fmaf(v.x, ss[0], ss[4]);
    v.y = fmaf(v.y, ss[1], ss[5]);
    v.z = fmaf(v.z, ss[2], ss[6]);
    v.w = fmaf(v.w, ss[3], ss[7]);
    reinterpret_cast<float4*>(out)[row] = v;
}

// ===========================================================================
// Fallback path (round-2 kernels) — used if ws_size is too small
// ===========================================================================
__global__ __launch_bounds__(256) void k_transpose_fb(const float* __restrict__ in,
                                                      float* __restrict__ out)
{
    int i = blockIdx.x * 256 + threadIdx.x;
    if (i < 787 * 64) {
        int k = i >> 6, o = i & 63;
        out[i] = in[o * 787 + k];
    }
}

#define SF1F(ic, r, c) sf1[(ic) * 324 + (r) * 20 + (c)]

__global__ __launch_bounds__(256) void k_fused_fb(
    const float* __restrict__ x,
    const float* __restrict__ w1, const float* __restrict__ b1,
    const float* __restrict__ w2, const float* __restrict__ b2,
    const float* __restrict__ s1w, const float* __restrict__ s1b,
    const float* __restrict__ s2w, const float* __restrict__ s2b,
    const float* __restrict__ fw, const float* __restrict__ fb,
    const float* __restrict__ wt, const float* __restrict__ fc1b,
    const float* __restrict__ fc2w, const float* __restrict__ fc2b,
    float* __restrict__ pre)
{
    const int b = blockIdx.x;
    const int t = threadIdx.x;

    __shared__ float sxA[30][20];
    __shared__ float sxB[30][20];
    __shared__ float sf1[8 * 324];
    __shared__ float scomb[788];
    __shared__ float sw1[72];
    __shared__ float sb1[8];
    __shared__ float sw2p[16 * 76];
    __shared__ float sb2[16];
    __shared__ float sh1p[4][64];
    __shared__ float sh1[64];
    __shared__ float sred[4];
    __shared__ float ssm[27];

    for (int i = t; i < 600; i += 256) { (&sxA[0][0])[i] = 0.f; (&sxB[0][0])[i] = 0.f; }
    for (int i = t; i < 8 * 324; i += 256) sf1[i] = 0.f;
    if (t < 72) sw1[t] = w1[t];
    if (t < 8) sb1[t] = b1[t];
    for (int i = t; i < 1152; i += 256) {
        int oc = i / 72, rem = i - oc * 72;
        sw2p[oc * 76 + rem] = w2[i];
    }
    if (t < 16) sb2[t] = b2[t];
    if (t < 8) ssm[t] = s1w[t];
    else if (t < 12) ssm[t] = s1b[t - 8];
    else if (t < 20) ssm[t] = s2w[t - 12];
    else if (t < 22) ssm[t] = s2b[t - 20];
    else if (t < 26) ssm[t] = fw[t - 22];
    else if (t == 26) ssm[t] = fb[0];
    __syncthreads();

    const float* xb = x + (size_t)b * 784;
    for (int i = t; i < 784; i += 256) {
        int r = i / 28, c = i - (i / 28) * 28;
        float v = xb[i];
        int pr = r + 1, pc = c + 1;
        if (pc <= 15) sxA[pr][pc] = v;
        if (pc >= 14) sxB[pr][pc - 14] = v;
    }
    __syncthreads();

    {
        const float fw00 = ssm[22], fw01 = ssm[23], fw10 = ssm[24], fw11 = ssm[25];
        const float fbv = ssm[26];
        float fsum = 0.f;
        for (int i = t; i < 729; i += 256) {
            int r = i / 27, c = i - (i / 27) * 27;
            float x00, x01, x10, x11;
            if (c <= 13) {
                x00 = sxA[r + 1][c + 1]; x01 = sxA[r + 1][c + 2];
                x10 = sxA[r + 2][c + 1]; x11 = sxA[r + 2][c + 2];
            } else {
                int cb = c - 14;
                x00 = sxB[r + 1][cb + 1]; x01 = sxB[r + 1][cb + 2];
                x10 = sxB[r + 2][cb + 1]; x11 = sxB[r + 2][cb + 2];
            }
            float v = fbv;
            v = fmaf(x00, fw00, v); v = fmaf(x01, fw01, v);
            v = fmaf(x10, fw10, v); v = fmaf(x11, fw11, v);
            fsum += 1.f / (1.f + expf(-v));
        }
        #pragma unroll
        for (int off = 32; off > 0; off >>= 1)
            fsum += __shfl_xor(fsum, off, 64);
        if ((t & 63) == 0) sred[t >> 6] = fsum;
    }

    {
        const int half = t >> 7;
        const int id = t & 127;
        if (id < 112) {
            const int p = id >> 3, oc = id & 7;
            const float* base = half ? &sxB[0][0] : &sxA[0][0];
            float X[4][16];
            #pragma unroll
            for (int u = 0; u < 4; ++u) {
                const float4* rp = reinterpret_cast<const float4*>(base + (2 * p + u) * 20);
                float4 a = rp[0], bb4 = rp[1], c4 = rp[2], d4 = rp[3];
                X[u][0] = a.x;  X[u][1] = a.y;  X[u][2] = a.z;  X[u][3] = a.w;
                X[u][4] = bb4.x; X[u][5] = bb4.y; X[u][6] = bb4.z; X[u][7] = bb4.w;
                X[u][8] = c4.x;  X[u][9] = c4.y;  X[u][10] = c4.z; X[u][11] = c4.w;
                X[u][12] = d4.x; X[u][13] = d4.y; X[u][14] = d4.z; X[u][15] = d4.w;
            }
            float W[9];
            #pragma unroll
            for (int k = 0; k < 9; ++k) W[k] = sw1[oc * 9 + k];
            const float bias = sb1[oc];
            const int j0 = half * 7;
            #pragma unroll
            for (int jj = 0; jj < 7; ++jj) {
                float m = 0.f;
                #pragma unroll
                for (int dr = 0; dr < 2; ++dr)
                    #pragma unroll
                    for (int dc = 0; dc < 2; ++dc) {
                        float acc = bias;
                        #pragma unroll
                        for (int u = 0; u < 3; ++u)
                            #pragma unroll
                            for (int v = 0; v < 3; ++v)
                                acc = fmaf(X[dr + u][2 * jj + dc + v], W[u * 3 + v], acc);
                        m = fmaxf(m, acc);
                    }
                SF1F(oc, p + 1, j0 + jj + 1) = m;
            }
        }
    }
    __syncthreads();

    if (t < 112) {
        const int p = t >> 4, oc = t & 15;
        const float bias = sb2[oc];
        float acc[7][4];
        #pragma unroll
        for (int jj = 0; jj < 7; ++jj)
            #pragma unroll
            for (int s = 0; s < 4; ++s) acc[jj][s] = bias;
        for (int ic = 0; ic < 8; ++ic) {
            float X[4][16];
            #pragma unroll
            for (int u = 0; u < 4; ++u) {
                const float4* rp = reinterpret_cast<const float4*>(&SF1F(ic, 2 * p + u, 0));
                float4 a = rp[0], bb4 = rp[1], c4 = rp[2], d4 = rp[3];
                X[u][0] = a.x;  X[u][1] = a.y;  X[u][2] = a.z;  X[u][3] = a.w;
                X[u][4] = bb4.x; X[u][5] = bb4.y; X[u][6] = bb4.z; X[u][7] = bb4.w;
                X[u][8] = c4.x;  X[u][9] = c4.y;  X[u][10] = c4.z; X[u][11] = c4.w;
                X[u][12] = d4.x; X[u][13] = d4.y; X[u][14] = d4.z; X[u][15] = d4.w;
            }
            float W[9];
            #pragma unroll
            for (int k = 0; k < 9; ++k) W[k] = sw2p[oc * 76 + ic * 9 + k];
            #pragma unroll
            for (int jj = 0; jj < 7; ++jj)
                #pragma unroll
                for (int dr = 0; dr < 2; ++dr)
                    #pragma unroll
                    for (int dc = 0; dc < 2; ++dc)
                        #pragma unroll
                        for (int u = 0; u < 3; ++u)
                            #pragma unroll
                            for (int v = 0; v < 3; ++v)
                                acc[jj][dr * 2 + dc] =
                                    fmaf(X[dr + u][2 * jj + dc + v], W[u * 3 + v], acc[jj][dr * 2 + dc]);
        }
        #pragma unroll
        for (int jj = 0; jj < 7; ++jj) {
            float m = fmaxf(fmaxf(acc[jj][0], acc[jj][1]), fmaxf(acc[jj][2], acc[jj][3]));
            scomb[oc * 49 + p * 7 + jj] = fmaxf(m, 0.f);
        }
    }
    __syncthreads();

    if (t == 0) {
        scomb[786] = (sred[0] + sred[1] + sred[2] + sred[3]) * (1.f / 729.f);
        float f0 = scomb[0], f1 = scomb[1];
        float h[4];
        #pragma unroll
        for (int k = 0; k < 4; ++k)
            h[k] = tanhf(fmaf(f0, ssm[k * 2], fmaf(f1, ssm[k * 2 + 1], ssm[8 + k])));
        float l0 = ssm[20], l1 = ssm[21];
        #pragma unroll
        for (int k = 0; k < 4; ++k) {
            l0 = fmaf(h[k], ssm[12 + k], l0);
            l1 = fmaf(h[k], ssm[16 + k], l1);
        }
        float mx = fmaxf(l0, l1);
        float e0 = expf(l0 - mx), e1 = expf(l1 - mx);
        float inv = 1.f / (e0 + e1);
        scomb[784] = e0 * inv;
        scomb[785] = e1 * inv;
    }
    __syncthreads();

    {
        const int o = t & 63, w = t >> 6;
        const int k0 = w * 197;
        const int k1 = (w == 3) ? 787 : k0 + 197;
        const float* wp = wt + (size_t)k0 * 64 + o;
        float acc = 0.f;
        #pragma unroll 4
        for (int k = k0; k < k1; ++k) {
            acc = fmaf(scomb[k], *wp, acc);
            wp += 64;
        }
        sh1p[w][o] = acc;
    }
    __syncthreads();
    if (t < 64)
        sh1[t] = fmaxf(sh1p[0][t] + sh1p[1][t] + sh1p[2][t] + sh1p[3][t] + fc1b[t], 0.f);
    __syncthreads();

    {
        const int oo = t >> 6, lane = t & 63;
        float v = sh1[lane] * fc2w[oo * 64 + lane];
        #pragma unroll
        for (int off = 32; off > 0; off >>= 1)
            v += __shfl_xor(v, off, 64);
        if (lane == 0) pre[(size_t)b * 4 + oo] = v + fc2b[oo];
    }
}

__global__ __launch_bounds__(256) void k_bnstat_fb(const float* __restrict__ pre,
                                                   float* __restrict__ part)
{
    const int t = threadIdx.x;
    const int row = blockIdx.x * 256 + t;
    float4 v = reinterpret_cast<const float4*>(pre)[row];
    float s0 = v.x, s1 = v.y, s2 = v.z, s3 = v.w;
    float q0 = v.x * v.x, q1 = v.y * v.y, q2 = v.z * v.z, q3 = v.w * v.w;
    #pragma unroll
    for (int off = 32; off > 0; off >>= 1) {
        s0 += __shfl_xor(s0, off, 64);
        s1 += __shfl_xor(s1, off, 64);
        s2 += __shfl_xor(s2, off, 64);
        s3 += __shfl_xor(s3, off, 64);
        q0 += __shfl_xor(q0, off, 64);
        q1 += __shfl_xor(q1, off, 64);
        q2 += __shfl_xor(q2, off, 64);
        q3 += __shfl_xor(q3, off, 64);
    }
    __shared__ float acc[4][8];
    if ((t & 63) == 0) {
        int w = t >> 6;
        acc[w][0] = s0; acc[w][1] = s1; acc[w][2] = s2; acc[w][3] = s3;
        acc[w][4] = q0; acc[w][5] = q1; acc[w][6] = q2; acc[w][7] = q3;
    }
    __syncthreads();
    if (t < 8)
        part[blockIdx.x * 8 + t] = acc[0][t] + acc[1][t] + acc[2][t] + acc[3][t];
}

// ===========================================================================
extern "C" void kernel_launch(void* const* d_in, const int* in_sizes, int n_in,
                              void* d_out, int out_size, void* d_ws, size_t ws_size,
                              hipStream_t stream)
{
    const float* x    = (const float*)d_in[0];
    const float* w1   = (const float*)d_in[1];
    const float* b1   = (const float*)d_in[2];
    const float* w2   = (const float*)d_in[3];
    const float* b2   = (const float*)d_in[4];
    const float* s1w  = (const float*)d_in[5];
    const float* s1b  = (const float*)d_in[6];
    const float* s2w  = (const float*)d_in[7];
    const float* s2b  = (const float*)d_in[8];
    const float* fw   = (const float*)d_in[9];
    const float* fb   = (const float*)d_in[10];
    const float* fc1w = (const float*)d_in[11];
    const float* fc1b = (const float*)d_in[12];
    const float* fc2w = (const float*)d_in[13];
    const float* fc2b = (const float*)d_in[14];
    const float* bng  = (const float*)d_in[15];
    const float* bnb  = (const float*)d_in[16];

    float* out = (float*)d_out;

    const size_t COMB_BYTES = (size_t)NBATCH * 800 * 2;          // 26,214,400
    const size_t WT_BYTES   = 64 * 800 * 2;                      // 102,400
    const size_t NEED = COMB_BYTES + WT_BYTES + 256 * 8 * 4 + 32;

    if (ws_size >= NEED) {
        unsigned short* comb = (unsigned short*)d_ws;
        unsigned short* wtbf = (unsigned short*)((char*)d_ws + COMB_BYTES);
        float* part = (float*)((char*)d_ws + COMB_BYTES + WT_BYTES);
        float* ss   = part + 256 * 8;

        k_prep<<<200, 256, 0, stream>>>(fc1w, wtbf);
        k_conv<<<NBATCH, 256, 0, stream>>>(x, w1, b1, w2, b2, s1w, s1b, s2w, s2b,
                                           fw, fb, comb);
        k_fc<<<256, 256, 0, stream>>>(comb, wtbf, fc1b, fc2w, fc2b, out, part);
        k_bnfinal<<<1, 64, 0, stream>>>(part, bng, bnb, ss, 256);
        k_bnapply<<<64, 256, 0, stream>>>(ss, out);
    } else {
        float* part = (float*)d_ws;
        float* ss   = part + 512;
        float* wt   = ss + 8;

        k_transpose_fb<<<197, 256, 0, stream>>>(fc1w, wt);
        k_fused_fb<<<NBATCH, 256, 0, stream>>>(x, w1, b1, w2, b2, s1w, s1b, s2w, s2b,
                                               fw, fb, wt, fc1b, fc2w, fc2b, out);
        k_bnstat_fb<<<64, 256, 0, stream>>>(out, part);
        k_bnfinal<<<1, 64, 0, stream>>>(part, bng, bnb, ss, 64);
        k_bnapply<<<64, 256, 0, stream>>>(ss, out);
    }
}

// Round 6
// 106.643 us; speedup vs baseline: 6.7495x; 1.0877x over previous
//
#include <hip/hip_runtime.h>
#include <hip/hip_fp16.h>
#include <math.h>

#define NBATCH 16384
#define EPSV 1e-5f
#define IMG 8

typedef short short8 __attribute__((ext_vector_type(8)));
typedef _Float16 half8_t __attribute__((ext_vector_type(8)));
typedef short short2v __attribute__((ext_vector_type(2)));
typedef float f32x4 __attribute__((ext_vector_type(4)));
union V8 { uint4 u; short8 s; };
union VH { uint4 u; half8_t h; };

__device__ __forceinline__ unsigned short f2bf(float f) {
    unsigned int x = __float_as_uint(f);
    return (unsigned short)((x + 0x7fffu + ((x >> 16) & 1u)) >> 16);  // RNE
}
__device__ __forceinline__ __half2 u2h(unsigned int u) { return __builtin_bit_cast(__half2, u); }
__device__ __forceinline__ unsigned int h2u(__half2 h) { return __builtin_bit_cast(unsigned int, h); }

// ---------------------------------------------------------------------------
// K0: prep all weight transforms once.
//   i <  51200 : wt bf16 [64][800]      (fc1w, K zero-padded)
//   i <  52736 : A_f16 [12][16][8]      (W2 MFMA-A layout, f16, slots 9..11 = 0)
//   i <  52808 : w1h2 [72] u32          (half2(w,w) duplicated conv1 weights)
//   i <  52816 : b1h2 [8] u32           (half2(b,b))
// ---------------------------------------------------------------------------
__global__ __launch_bounds__(256) void k_prep(
    const float* __restrict__ fc1w, const float* __restrict__ w2,
    const float* __restrict__ w1, const float* __restrict__ b1,
    unsigned short* __restrict__ wt, unsigned short* __restrict__ af16,
    unsigned int* __restrict__ w1h2, unsigned int* __restrict__ b1h2)
{
    int i = blockIdx.x * 256 + threadIdx.x;
    if (i < 51200) {
        int n = i / 800, k = i - n * 800;
        float v = (k < 787) ? fc1w[n * 787 + k] : 0.f;
        wt[i] = f2bf(v);
    } else if (i < 52736) {
        int a = i - 51200;
        int slot = a >> 7, rem = a & 127, oc = rem >> 3, ic = rem & 7;
        float v = (slot < 9) ? w2[oc * 72 + ic * 9 + slot] : 0.f;
        af16[a] = __half_as_ushort(__float2half(v));
    } else if (i < 52808) {
        int k = i - 52736;
        unsigned int hb = __half_as_ushort(__float2half(w1[k]));
        w1h2[k] = hb | (hb << 16);
    } else if (i < 52816) {
        int k = i - 52808;
        unsigned int hb = __half_as_ushort(__float2half(b1[k]));
        b1h2[k] = hb | (hb << 16);
    }
}

// ---------------------------------------------------------------------------
// K1: IMG images per 256-thread block. conv1 in packed f16, conv2 via f16
//     MFMA (channels-last), filter conv in packed f16, sampler, bf16 pack.
// ---------------------------------------------------------------------------
__global__ __launch_bounds__(256) void k_conv(
    const float* __restrict__ x,
    const float* __restrict__ s1w, const float* __restrict__ s1b,
    const float* __restrict__ s2w, const float* __restrict__ s2b,
    const float* __restrict__ fw, const float* __restrict__ fb,
    const float* __restrict__ b2,
    const unsigned short* __restrict__ Afg,   // [12][16][8] f16
    const unsigned int* __restrict__ w1h2g,   // [72]
    const unsigned int* __restrict__ b1h2g,   // [8]
    unsigned short* __restrict__ comb)
{
    const int t = threadIdx.x;
    const int b_base = blockIdx.x * IMG;

    // padded 30x30 input as f16 col-pairs: row stride 18 u32 (72B, 8B-aligned,
    // bank = (18r + cp) mod 32 -> <=2-way). Half idx c == P col c.
    __shared__ unsigned int sxu[30 * 18];
    // conv1 pooled out, channels-last f16: cell (R,C) = 8 f16, row stride 136 ush
    __shared__ __align__(16) unsigned short sf1[16 * 136];
    __shared__ __align__(16) float scomb[800];
    __shared__ float sred[4];
    __shared__ float ssm[27];       // s1w(8) s1b(4) s2w(8) s2b(2) fw(4) fb(1)
    __shared__ float sb2s[16];

    // ---------------- block prologue (once per 8 images) --------------------
    for (int i = t; i < 540; i += 256) sxu[i] = 0u;
    if (t < 60) {   // sf1 pad ring
        int R, C;
        if (t < 16)      { R = 0;      C = t; }
        else if (t < 32) { R = 15;     C = t - 16; }
        else if (t < 46) { R = t - 31; C = 0; }
        else             { R = t - 45; C = 15; }
        *reinterpret_cast<uint4*>(&sf1[R * 136 + C * 8]) = uint4{0u, 0u, 0u, 0u};
    }
    if (t >= 64 && t < 80) scomb[784 + (t - 64)] = 0.f;
    if (t >= 128 && t < 136) ssm[t - 128] = s1w[t - 128];
    else if (t >= 136 && t < 140) ssm[t - 128] = s1b[t - 136];
    else if (t >= 140 && t < 148) ssm[t - 128] = s2w[t - 140];
    else if (t >= 148 && t < 150) ssm[t - 128] = s2b[t - 148];
    else if (t >= 150 && t < 154) ssm[t - 128] = fw[t - 150];
    else if (t == 154) ssm[26] = fb[0];
    if (t >= 160 && t < 176) sb2s[t - 160] = b2[t - 160];
    __syncthreads();

    // filter weights as half2 duplicates (registers, all threads)
    const __half2 fwh0 = __float2half2_rn(ssm[22]);
    const __half2 fwh1 = __float2half2_rn(ssm[23]);
    const __half2 fwh2 = __float2half2_rn(ssm[24]);
    const __half2 fwh3 = __float2half2_rn(ssm[25]);
    const __half2 fbh  = __float2half2_rn(ssm[26]);

    // conv2 MFMA A-fragments + B offsets (invariant across images)
    const int l = t & 63, w = t >> 6;
    const int n = l & 15, g = l >> 4;
    const int qr = n & 7;
    const int q = (qr < 7) ? qr : 6;
    const int dr = n >> 3;
    int offs[3];
    VH af[3];
    #pragma unroll
    for (int s = 0; s < 3; ++s) {
        const int slot = s * 4 + g;
        const int u = slot / 3, v = slot - 3 * (slot / 3);
        offs[s] = (slot <= 8) ? (u * 136 + v * 8) : 0;
        af[s].u = *reinterpret_cast<const uint4*>(Afg + ((slot * 16 + n) << 3));
    }

    // ---------------- image loop --------------------------------------------
    for (int img = 0; img < IMG; ++img) {
        const int b = b_base + img;
        const float* xb = x + (size_t)b * 784;

        // ---- stage x -> f16 col-pairs (28 rows x 15 u32 units)
        for (int u0 = t; u0 < 420; u0 += 256) {
            int r = u0 / 15, ww = u0 - r * 15;
            __half2 h2;
            if (ww == 0)       h2 = __floats2half2_rn(0.f, xb[r * 28]);
            else if (ww == 14) h2 = __floats2half2_rn(xb[r * 28 + 27], 0.f);
            else               h2 = __floats2half2_rn(xb[r * 28 + 2 * ww - 1],
                                                      xb[r * 28 + 2 * ww]);
            sxu[(r + 1) * 18 + ww] = h2u(h2);
        }
        __syncthreads();

        // ---- filter conv (2 positions per unit, packed f16) + sigmoid sums
        {
            float fsum = 0.f;
            #pragma unroll
            for (int it = 0; it < 2; ++it) {
                int u0 = t + it * 256;
                if (u0 < 378) {
                    int r = u0 / 14, cp = u0 - (u0 / 14) * 14;
                    unsigned int A1 = sxu[(r + 1) * 18 + cp], B1 = sxu[(r + 1) * 18 + cp + 1];
                    unsigned int A2 = sxu[(r + 2) * 18 + cp], B2 = sxu[(r + 2) * 18 + cp + 1];
                    __half2 al1 = u2h(__builtin_amdgcn_alignbit(B1, A1, 16));
                    __half2 al2 = u2h(__builtin_amdgcn_alignbit(B2, A2, 16));
                    __half2 acc = __hfma2(fwh0, al1,
                                  __hfma2(fwh1, u2h(B1),
                                  __hfma2(fwh2, al2,
                                  __hfma2(fwh3, u2h(B2), fbh))));
                    float2 f = __half22float2(acc);
                    fsum += __frcp_rn(1.f + __expf(-f.x));
                    if (cp < 13) fsum += __frcp_rn(1.f + __expf(-f.y));
                }
            }
            #pragma unroll
            for (int off = 32; off > 0; off >>= 1)
                fsum += __shfl_xor(fsum, off, 64);
            if ((t & 63) == 0) sred[t >> 6] = fsum;
        }

        // ---- conv1: thread (p,j) computes pooled cell (p,j), 8 oc, packed f16
        if (t < 196) {
            const int p = t / 14, j = t - (t / 14) * 14;
            unsigned int A[4], B[4], M[4];
            #pragma unroll
            for (int u = 0; u < 4; ++u) {
                A[u] = sxu[(2 * p + u) * 18 + j];
                B[u] = sxu[(2 * p + u) * 18 + j + 1];
                M[u] = __builtin_amdgcn_alignbit(B[u], A[u], 16);
            }
            unsigned short outv[8];
            #pragma unroll
            for (int oc = 0; oc < 8; ++oc) {
                __half2 a0 = u2h(b1h2g[oc]), a1 = a0;   // (dc0, dc1) for dr=0 / dr=1
                #pragma unroll
                for (int u = 0; u < 3; ++u) {
                    #pragma unroll
                    for (int v = 0; v < 3; ++v) {
                        const __half2 wv = u2h(w1h2g[oc * 9 + u * 3 + v]);
                        const unsigned int p0 = (v == 0) ? A[u]     : ((v == 1) ? M[u]     : B[u]);
                        const unsigned int p1 = (v == 0) ? A[u + 1] : ((v == 1) ? M[u + 1] : B[u + 1]);
                        a0 = __hfma2(wv, u2h(p0), a0);
                        a1 = __hfma2(wv, u2h(p1), a1);
                    }
                }
                // relu(max of 4) via signed-short max (valid with 0 clamp)
                short2v s0 = __builtin_bit_cast(short2v, a0);
                short2v s1 = __builtin_bit_cast(short2v, a1);
                short2v mm = __builtin_elementwise_max(s0, s1);
                short m = mm[0] > mm[1] ? mm[0] : mm[1];
                if (m < 0) m = 0;
                outv[oc] = (unsigned short)m;
            }
            *reinterpret_cast<uint4*>(&sf1[(p + 1) * 136 + (j + 1) * 8]) =
                *reinterpret_cast<const uint4*>(outv);
        }
        __syncthreads();

        // ---- conv2 via f16 MFMA: D[16 oc][16 pos], pool by reg-max + shfl
        for (int pp = w; pp < 7; pp += 4) {
            const int rbase = (2 * pp + dr) * 136 + (2 * q) * 8;
            f32x4 acc0 = {0.f, 0.f, 0.f, 0.f}, acc1 = {0.f, 0.f, 0.f, 0.f};
            #pragma unroll
            for (int s = 0; s < 3; ++s) {
                VH b0, b1v;
                b0.u  = *reinterpret_cast<const uint4*>(&sf1[rbase + offs[s]]);
                b1v.u = *reinterpret_cast<const uint4*>(&sf1[rbase + 8 + offs[s]]);
                acc0 = __builtin_amdgcn_mfma_f32_16x16x32_f16(af[s].h, b0.h, acc0, 0, 0, 0);
                acc1 = __builtin_amdgcn_mfma_f32_16x16x32_f16(af[s].h, b1v.h, acc1, 0, 0, 0);
            }
            #pragma unroll
            for (int i = 0; i < 4; ++i) {
                const float bias = sb2s[4 * g + i];
                float m = fmaxf(acc0[i], acc1[i]);
                m = fmaxf(m, __shfl_xor(m, 8, 64));
                if (n < 7)
                    scomb[(4 * g + i) * 49 + pp * 7 + q] = fmaxf(m + bias, 0.f);
            }
        }
        __syncthreads();

        // ---- sampler + filter-mean finalize
        if (t == 0) {
            scomb[786] = (sred[0] + sred[1] + sred[2] + sred[3]) * (1.f / 729.f);
            float f0 = scomb[0], f1 = scomb[1];
            float h[4];
            #pragma unroll
            for (int k = 0; k < 4; ++k) {
                float y = fmaf(f0, ssm[k * 2], fmaf(f1, ssm[k * 2 + 1], ssm[8 + k]));
                float e = __expf(2.f * y);
                h[k] = (e - 1.f) * __frcp_rn(e + 1.f);
            }
            float l0 = ssm[20], l1 = ssm[21];
            #pragma unroll
            for (int k = 0; k < 4; ++k) {
                l0 = fmaf(h[k], ssm[12 + k], l0);
                l1 = fmaf(h[k], ssm[16 + k], l1);
            }
            float mx = fmaxf(l0, l1);
            float e0 = __expf(l0 - mx), e1 = __expf(l1 - mx);
            float inv = __frcp_rn(e0 + e1);
            scomb[784] = e0 * inv;
            scomb[785] = e1 * inv;
        }
        __syncthreads();

        // ---- pack scomb -> combined bf16 row [800]
        if (t < 100) {
            const float4* sp = reinterpret_cast<const float4*>(scomb);
            float4 f0 = sp[2 * t], f1 = sp[2 * t + 1];
            uint4 o;
            o.x = (unsigned int)f2bf(f0.x) | ((unsigned int)f2bf(f0.y) << 16);
            o.y = (unsigned int)f2bf(f0.z) | ((unsigned int)f2bf(f0.w) << 16);
            o.z = (unsigned int)f2bf(f1.x) | ((unsigned int)f2bf(f1.y) << 16);
            o.w = (unsigned int)f2bf(f1.z) | ((unsigned int)f2bf(f1.w) << 16);
            reinterpret_cast<uint4*>(comb)[(size_t)b * 100 + t] = o;
        }
        __syncthreads();
    }
}

// ---------------------------------------------------------------------------
// K2: MFMA GEMM  h1 = relu(comb[16384,800] @ wt[64,800]^T + fc1b)
//     epilogue: out = h1 @ fc2w^T + fc2b  (+ per-block BN partial stats)
// ---------------------------------------------------------------------------
__global__ __launch_bounds__(256) void k_fc(
    const unsigned short* __restrict__ A,
    const unsigned short* __restrict__ Bw,
    const float* __restrict__ fc1b,
    const float* __restrict__ fc2w, const float* __restrict__ fc2b,
    float* __restrict__ out, float* __restrict__ part)
{
    __shared__ uint4 Asm[2][256];
    __shared__ uint4 Bsm[2][256];
    __shared__ float sh[64][68];
    __shared__ float sfc2[4][64];
    __shared__ float pacc[4][8];

    const int t = threadIdx.x;
    const int w = t >> 6, l = t & 63;
    const int blk = blockIdx.x;

    sfc2[t >> 6][t & 63] = fc2w[t];

    const int srow = t >> 2, skbp = t & 3;
    const int skbl = skbp ^ ((srow >> 1) & 3);
    const uint4* Ag = reinterpret_cast<const uint4*>(A) + ((size_t)blk * 64 + srow) * 100;
    const uint4* Bg = reinterpret_cast<const uint4*>(Bw) + (size_t)srow * 100;
    const int sidx = srow * 4 + skbp;

    const int arow = w * 16 + (l & 15);
    const int aidx = arow * 4 + ((l >> 4) ^ ((arow >> 1) & 3));
    int bidx[4];
    #pragma unroll
    for (int nf = 0; nf < 4; ++nf) {
        int nn = nf * 16 + (l & 15);
        bidx[nf] = nn * 4 + ((l >> 4) ^ ((nn >> 1) & 3));
    }

    f32x4 acc0 = {0.f, 0.f, 0.f, 0.f}, acc1 = acc0, acc2 = acc0, acc3 = acc0;

    Asm[0][sidx] = Ag[skbl];
    Bsm[0][sidx] = Bg[skbl];

    int buf = 0;
    for (int s = 0; s < 25; ++s) {
        __syncthreads();
        if (s < 24) {
            Asm[buf ^ 1][sidx] = Ag[(s + 1) * 4 + skbl];
            Bsm[buf ^ 1][sidx] = Bg[(s + 1) * 4 + skbl];
        }
        V8 av; av.u = Asm[buf][aidx];
        V8 b0; b0.u = Bsm[buf][bidx[0]];
        V8 b1; b1.u = Bsm[buf][bidx[1]];
        V8 b2; b2.u = Bsm[buf][bidx[2]];
        V8 b3; b3.u = Bsm[buf][bidx[3]];
        acc0 = __builtin_amdgcn_mfma_f32_16x16x32_bf16(av.s, b0.s, acc0, 0, 0, 0);
        acc1 = __builtin_amdgcn_mfma_f32_16x16x32_bf16(av.s, b1.s, acc1, 0, 0, 0);
        acc2 = __builtin_amdgcn_mfma_f32_16x16x32_bf16(av.s, b2.s, acc2, 0, 0, 0);
        acc3 = __builtin_amdgcn_mfma_f32_16x16x32_bf16(av.s, b3.s, acc3, 0, 0, 0);
        buf ^= 1;
    }

    {
        const int c0 = l & 15, r0 = w * 16 + (l >> 4) * 4;
        float fb0 = fc1b[c0], fb1 = fc1b[16 + c0], fb2 = fc1b[32 + c0], fb3 = fc1b[48 + c0];
        #pragma unroll
        for (int r = 0; r < 4; ++r) {
            sh[r0 + r][c0]      = fmaxf(acc0[r] + fb0, 0.f);
            sh[r0 + r][16 + c0] = fmaxf(acc1[r] + fb1, 0.f);
            sh[r0 + r][32 + c0] = fmaxf(acc2[r] + fb2, 0.f);
            sh[r0 + r][48 + c0] = fmaxf(acc3[r] + fb3, 0.f);
        }
    }
    __syncthreads();

    {
        const int row = t >> 2, oo = t & 3;
        float s = fc2b[oo];
        #pragma unroll 8
        for (int o = 0; o < 64; ++o)
            s = fmaf(sh[row][o], sfc2[oo][o], s);
        out[((size_t)blk * 64 + row) * 4 + oo] = s;

        float rs = s, rq = s * s;
        #pragma unroll
        for (int off = 4; off < 64; off <<= 1) {
            rs += __shfl_xor(rs, off, 64);
            rq += __shfl_xor(rq, off, 64);
        }
        if (l < 4) pacc[w][l] = rs;
        else if (l < 8) pacc[w][l] = rq;
    }
    __syncthreads();
    if (t < 8)
        part[blk * 8 + t] = pacc[0][t] + pacc[1][t] + pacc[2][t] + pacc[3][t];
}

// ---------------------------------------------------------------------------
// BN finalize + apply
// ---------------------------------------------------------------------------
__global__ void k_bnfinal(const float* __restrict__ part,
                          const float* __restrict__ g, const float* __restrict__ bb,
                          float* __restrict__ ss, int nblocks)
{
    const int t = threadIdx.x;  // 64
    float s[8];
    #pragma unroll
    for (int i = 0; i < 8; ++i) s[i] = 0.f;
    for (int idx = t; idx < nblocks; idx += 64)
        #pragma unroll
        for (int i = 0; i < 8; ++i) s[i] += part[idx * 8 + i];
    #pragma unroll
    for (int i = 0; i < 8; ++i)
        #pragma unroll
        for (int off = 32; off > 0; off >>= 1)
            s[i] += __shfl_xor(s[i], off, 64);
    if (t == 0) {
        const float invB = 1.f / 16384.f;
        #pragma unroll
        for (int j = 0; j < 4; ++j) {
            float mu = s[j] * invB;
            float var = s[4 + j] * invB - mu * mu;
            float sc = g[j] * rsqrtf(var + EPSV);
            ss[j] = sc;
            ss[4 + j] = bb[j] - mu * sc;
        }
    }
}

__global__ __launch_bounds__(256) void k_bnapply(const float* __restrict__ ss,
                                                 float* __restrict__ out)
{
    const int row = blockIdx.x * 256 + threadIdx.x;
    float4 v = reinterpret_cast<float4*>(out)[row];
    v.x = fmaf(v.x, ss[0], ss[4]);
    v.y = fmaf(v.y, ss[1], ss[5]);
    v.z = fmaf(v.z, ss[2], ss[6]);
    v.w = fmaf(v.w, ss[3], ss[7]);
    reinterpret_cast<float4*>(out)[row] = v;
}

// ===========================================================================
// Fallback path (round-2 kernels) — used if ws_size is too small
// ===========================================================================
__global__ __launch_bounds__(256) void k_transpose_fb(const float* __restrict__ in,
                                                      float* __restrict__ out)
{
    int i = blockIdx.x * 256 + threadIdx.x;
    if (i < 787 * 64) {
        int k = i >> 6, o = i & 63;
        out[i] = in[o * 787 + k];
    }
}

#define SF1F(ic, r, c) sf1[(ic) * 324 + (r) * 20 + (c)]

__global__ __launch_bounds__(256) void k_fused_fb(
    const float* __restrict__ x,
    const float* __restrict__ w1, const float* __restrict__ b1,
    const float* __restrict__ w2, const float* __restrict__ b2,
    const float* __restrict__ s1w, const float* __restrict__ s1b,
    const float* __restrict__ s2w, const float* __restrict__ s2b,
    const float* __restrict__ fw, const float* __restrict__ fb,
    const float* __restrict__ wt, const float* __restrict__ fc1b,
    const float* __restrict__ fc2w, const float* __restrict__ fc2b,
    float* __restrict__ pre)
{
    const int b = blockIdx.x;
    const int t = threadIdx.x;

    __shared__ float sxA[30][20];
    __shared__ float sxB[30][20];
    __shared__ float sf1[8 * 324];
    __shared__ float scomb[788];
    __shared__ float sw1[72];
    __shared__ float sb1[8];
    __shared__ float sw2p[16 * 76];
    __shared__ float sb2[16];
    __shared__ float sh1p[4][64];
    __shared__ float sh1[64];
    __shared__ float sred[4];
    __shared__ float ssm[27];

    for (int i = t; i < 600; i += 256) { (&sxA[0][0])[i] = 0.f; (&sxB[0][0])[i] = 0.f; }
    for (int i = t; i < 8 * 324; i += 256) sf1[i] = 0.f;
    if (t < 72) sw1[t] = w1[t];
    if (t < 8) sb1[t] = b1[t];
    for (int i = t; i < 1152; i += 256) {
        int oc = i / 72, rem = i - oc * 72;
        sw2p[oc * 76 + rem] = w2[i];
    }
    if (t < 16) sb2[t] = b2[t];
    if (t < 8) ssm[t] = s1w[t];
    else if (t < 12) ssm[t] = s1b[t - 8];
    else if (t < 20) ssm[t] = s2w[t - 12];
    else if (t < 22) ssm[t] = s2b[t - 20];
    else if (t < 26) ssm[t] = fw[t - 22];
    else if (t == 26) ssm[t] = fb[0];
    __syncthreads();

    const float* xb = x + (size_t)b * 784;
    for (int i = t; i < 784; i += 256) {
        int r = i / 28, c = i - (i / 28) * 28;
        float v = xb[i];
        int pr = r + 1, pc = c + 1;
        if (pc <= 15) sxA[pr][pc] = v;
        if (pc >= 14) sxB[pr][pc - 14] = v;
    }
    __syncthreads();

    {
        const float fw00 = ssm[22], fw01 = ssm[23], fw10 = ssm[24], fw11 = ssm[25];
        const float fbv = ssm[26];
        float fsum = 0.f;
        for (int i = t; i < 729; i += 256) {
            int r = i / 27, c = i - (i / 27) * 27;
            float x00, x01, x10, x11;
            if (c <= 13) {
                x00 = sxA[r + 1][c + 1]; x01 = sxA[r + 1][c + 2];
                x10 = sxA[r + 2][c + 1]; x11 = sxA[r + 2][c + 2];
            } else {
                int cb = c - 14;
                x00 = sxB[r + 1][cb + 1]; x01 = sxB[r + 1][cb + 2];
                x10 = sxB[r + 2][cb + 1]; x11 = sxB[r + 2][cb + 2];
            }
            float v = fbv;
            v = fmaf(x00, fw00, v); v = fmaf(x01, fw01, v);
            v = fmaf(x10, fw10, v); v = fmaf(x11, fw11, v);
            fsum += 1.f / (1.f + expf(-v));
        }
        #pragma unroll
        for (int off = 32; off > 0; off >>= 1)
            fsum += __shfl_xor(fsum, off, 64);
        if ((t & 63) == 0) sred[t >> 6] = fsum;
    }

    {
        const int half = t >> 7;
        const int id = t & 127;
        if (id < 112) {
            const int p = id >> 3, oc = id & 7;
            const float* base = half ? &sxB[0][0] : &sxA[0][0];
            float X[4][16];
            #pragma unroll
            for (int u = 0; u < 4; ++u) {
                const float4* rp = reinterpret_cast<const float4*>(base + (2 * p + u) * 20);
                float4 a = rp[0], bb4 = rp[1], c4 = rp[2], d4 = rp[3];
                X[u][0] = a.x;  X[u][1] = a.y;  X[u][2] = a.z;  X[u][3] = a.w;
                X[u][4] = bb4.x; X[u][5] = bb4.y; X[u][6] = bb4.z; X[u][7] = bb4.w;
                X[u][8] = c4.x;  X[u][9] = c4.y;  X[u][10] = c4.z; X[u][11] = c4.w;
                X[u][12] = d4.x; X[u][13] = d4.y; X[u][14] = d4.z; X[u][15] = d4.w;
            }
            float W[9];
            #pragma unroll
            for (int k = 0; k < 9; ++k) W[k] = sw1[oc * 9 + k];
            const float bias = sb1[oc];
            const int j0 = half * 7;
            #pragma unroll
            for (int jj = 0; jj < 7; ++jj) {
                float m = 0.f;
                #pragma unroll
                for (int dr = 0; dr < 2; ++dr)
                    #pragma unroll
                    for (int dc = 0; dc < 2; ++dc) {
                        float acc = bias;
                        #pragma unroll
                        for (int u = 0; u < 3; ++u)
                            #pragma unroll
                            for (int v = 0; v < 3; ++v)
                                acc = fmaf(X[dr + u][2 * jj + dc + v], W[u * 3 + v], acc);
                        m = fmaxf(m, acc);
                    }
                SF1F(oc, p + 1, j0 + jj + 1) = m;
            }
        }
    }
    __syncthreads();

    if (t < 112) {
        const int p = t >> 4, oc = t & 15;
        const float bias = sb2[oc];
        float acc[7][4];
        #pragma unroll
        for (int jj = 0; jj < 7; ++jj)
            #pragma unroll
            for (int s = 0; s < 4; ++s) acc[jj][s] = bias;
        for (int ic = 0; ic < 8; ++ic) {
            float X[4][16];
            #pragma unroll
            for (int u = 0; u < 4; ++u) {
                const float4* rp = reinterpret_cast<const float4*>(&SF1F(ic, 2 * p + u, 0));
                float4 a = rp[0], bb4 = rp[1], c4 = rp[2], d4 = rp[3];
                X[u][0] = a.x;  X[u][1] = a.y;  X[u][2] = a.z;  X[u][3] = a.w;
                X[u][4] = bb4.x; X[u][5] = bb4.y; X[u][6] = bb4.z; X[u][7] = bb4.w;
                X[u][8] = c4.x;  X[u][9] = c4.y;  X[u][10] = c4.z; X[u][11] = c4.w;
                X[u][12] = d4.x; X[u][13] = d4.y; X[u][14] = d4.z; X[u][15] = d4.w;
            }
            float W[9];
            #pragma unroll
            for (int k = 0; k < 9; ++k) W[k] = sw2p[oc * 76 + ic * 9 + k];
            #pragma unroll
            for (int jj = 0; jj < 7; ++jj)
                #pragma unroll
                for (int dr = 0; dr < 2; ++dr)
                    #pragma unroll
                    for (int dc = 0; dc < 2; ++dc)
                        #pragma unroll
                        for (int u = 0; u < 3; ++u)
                            #pragma unroll
                            for (int v = 0; v < 3; ++v)
                                acc[jj][dr * 2 + dc] =
                                    fmaf(X[dr + u][2 * jj + dc + v], W[u * 3 + v], acc[jj][dr * 2 + dc]);
        }
        #pragma unroll
        for (int jj = 0; jj < 7; ++jj) {
            float m = fmaxf(fmaxf(acc[jj][0], acc[jj][1]), fmaxf(acc[jj][2], acc[jj][3]));
            scomb[oc * 49 + p * 7 + jj] = fmaxf(m, 0.f);
        }
    }
    __syncthreads();

    if (t == 0) {
        scomb[786] = (sred[0] + sred[1] + sred[2] + sred[3]) * (1.f / 729.f);
        float f0 = scomb[0], f1 = scomb[1];
        float h[4];
        #pragma unroll
        for (int k = 0; k < 4; ++k)
            h[k] = tanhf(fmaf(f0, ssm[k * 2], fmaf(f1, ssm[k * 2 + 1], ssm[8 + k])));
        float l0 = ssm[20], l1 = ssm[21];
        #pragma unroll
        for (int k = 0; k < 4; ++k) {
            l0 = fmaf(h[k], ssm[12 + k], l0);
            l1 = fmaf(h[k], ssm[16 + k], l1);
        }
        float mx = fmaxf(l0, l1);
        float e0 = expf(l0 - mx), e1 = expf(l1 - mx);
        float inv = 1.f / (e0 + e1);
        scomb[784] = e0 * inv;
        scomb[785] = e1 * inv;
    }
    __syncthreads();

    {
        const int o = t & 63, w = t >> 6;
        const int k0 = w * 197;
        const int k1 = (w == 3) ? 787 : k0 + 197;
        const float* wp = wt + (size_t)k0 * 64 + o;
        float acc = 0.f;
        #pragma unroll 4
        for (int k = k0; k < k1; ++k) {
            acc = fmaf(scomb[k], *wp, acc);
            wp += 64;
        }
        sh1p[w][o] = acc;
    }
    __syncthreads();
    if (t < 64)
        sh1[t] = fmaxf(sh1p[0][t] + sh1p[1][t] + sh1p[2][t] + sh1p[3][t] + fc1b[t], 0.f);
    __syncthreads();

    {
        const int oo = t >> 6, lane = t & 63;
        float v = sh1[lane] * fc2w[oo * 64 + lane];
        #pragma unroll
        for (int off = 32; off > 0; off >>= 1)
            v += __shfl_xor(v, off, 64);
        if (lane == 0) pre[(size_t)b * 4 + oo] = v + fc2b[oo];
    }
}

__global__ __launch_bounds__(256) void k_bnstat_fb(const float* __restrict__ pre,
                                                   float* __restrict__ part)
{
    const int t = threadIdx.x;
    const int row = blockIdx.x * 256 + t;
    float4 v = reinterpret_cast<const float4*>(pre)[row];
    float s0 = v.x, s1 = v.y, s2 = v.z, s3 = v.w;
    float q0 = v.x * v.x, q1 = v.y * v.y, q2 = v.z * v.z, q3 = v.w * v.w;
    #pragma unroll
    for (int off = 32; off > 0; off >>= 1) {
        s0 += __shfl_xor(s0, off, 64);
        s1 += __shfl_xor(s1, off, 64);
        s2 += __shfl_xor(s2, off, 64);
        s3 += __shfl_xor(s3, off, 64);
        q0 += __shfl_xor(q0, off, 64);
        q1 += __shfl_xor(q1, off, 64);
        q2 += __shfl_xor(q2, off, 64);
        q3 += __shfl_xor(q3, off, 64);
    }
    __shared__ float acc[4][8];
    if ((t & 63) == 0) {
        int w = t >> 6;
        acc[w][0] = s0; acc[w][1] = s1; acc[w][2] = s2; acc[w][3] = s3;
        acc[w][4] = q0; acc[w][5] = q1; acc[w][6] = q2; acc[w][7] = q3;
    }
    __syncthreads();
    if (t < 8)
        part[blockIdx.x * 8 + t] = acc[0][t] + acc[1][t] + acc[2][t] + acc[3][t];
}

// ===========================================================================
extern "C" void kernel_launch(void* const* d_in, const int* in_sizes, int n_in,
                              void* d_out, int out_size, void* d_ws, size_t ws_size,
                              hipStream_t stream)
{
    const float* x    = (const float*)d_in[0];
    const float* w1   = (const float*)d_in[1];
    const float* b1   = (const float*)d_in[2];
    const float* w2   = (const float*)d_in[3];
    const float* b2   = (const float*)d_in[4];
    const float* s1w  = (const float*)d_in[5];
    const float* s1b  = (const float*)d_in[6];
    const float* s2w  = (const float*)d_in[7];
    const float* s2b  = (const float*)d_in[8];
    const float* fw   = (const float*)d_in[9];
    const float* fb   = (const float*)d_in[10];
    const float* fc1w = (const float*)d_in[11];
    const float* fc1b = (const float*)d_in[12];
    const float* fc2w = (const float*)d_in[13];
    const float* fc2b = (const float*)d_in[14];
    const float* bng  = (const float*)d_in[15];
    const float* bnb  = (const float*)d_in[16];

    float* out = (float*)d_out;

    const size_t COMB_BYTES = (size_t)NBATCH * 800 * 2;      // 26,214,400
    const size_t WT_BYTES   = 64 * 800 * 2;                  // 102,400
    const size_t AF16_BYTES = 1536 * 2;                      // 3,072
    const size_t W1H2_BYTES = 72 * 4;                        // 288
    const size_t B1H2_BYTES = 8 * 4;                         // 32
    const size_t PART_BYTES = 256 * 8 * 4;                   // 8,192
    const size_t NEED = COMB_BYTES + WT_BYTES + AF16_BYTES + W1H2_BYTES +
                        B1H2_BYTES + PART_BYTES + 32;

    if (ws_size >= NEED) {
        char* p = (char*)d_ws;
        unsigned short* comb = (unsigned short*)p;                     p += COMB_BYTES;
        unsigned short* wtbf = (unsigned short*)p;                     p += WT_BYTES;
        unsigned short* af16 = (unsigned short*)p;                     p += AF16_BYTES;
        unsigned int*   w1h2 = (unsigned int*)p;                       p += W1H2_BYTES;
        unsigned int*   b1h2 = (unsigned int*)p;                       p += B1H2_BYTES;
        float*          part = (float*)p;                              p += PART_BYTES;
        float*          ss   = (float*)p;

        k_prep<<<207, 256, 0, stream>>>(fc1w, w2, w1, b1, wtbf, af16, w1h2, b1h2);
        k_conv<<<NBATCH / IMG, 256, 0, stream>>>(x, s1w, s1b, s2w, s2b, fw, fb, b2,
                                                 af16, w1h2, b1h2, comb);
        k_fc<<<256, 256, 0, stream>>>(comb, wtbf, fc1b, fc2w, fc2b, out, part);
        k_bnfinal<<<1, 64, 0, stream>>>(part, bng, bnb, ss, 256);
        k_bnapply<<<64, 256, 0, stream>>>(ss, out);
    } else {
        float* part = (float*)d_ws;
        float* ss   = part + 512;
        float* wt   = ss + 8;

        k_transpose_fb<<<197, 256, 0, stream>>>(fc1w, wt);
        k_fused_fb<<<NBATCH, 256, 0, stream>>>(x, w1, b1, w2, b2, s1w, s1b, s2w, s2b,
                                               fw, fb, wt, fc1b, fc2w, fc2b, out);
        k_bnstat_fb<<<64, 256, 0, stream>>>(out, part);
        k_bnfinal<<<1, 64, 0, stream>>>(part, bng, bnb, ss, 64);
        k_bnapply<<<64, 256, 0, stream>>>(ss, out);
    }
}

// Round 7
// 105.274 us; speedup vs baseline: 6.8372x; 1.0130x over previous
//
#include <hip/hip_runtime.h>
#include <hip/hip_fp16.h>
#include <math.h>

#define NBATCH 16384
#define EPSV 1e-5f
#define IMGW 4   // images per wave

typedef short short8 __attribute__((ext_vector_type(8)));
typedef _Float16 half8_t __attribute__((ext_vector_type(8)));
typedef short short2v __attribute__((ext_vector_type(2)));
typedef float f32x4 __attribute__((ext_vector_type(4)));
union V8 { uint4 u; short8 s; };
union VH { uint4 u; half8_t h; };

__device__ __forceinline__ unsigned short f2bf(float f) {
    unsigned int x = __float_as_uint(f);
    return (unsigned short)((x + 0x7fffu + ((x >> 16) & 1u)) >> 16);  // RNE
}
__device__ __forceinline__ __half2 u2h(unsigned int u) { return __builtin_bit_cast(__half2, u); }
__device__ __forceinline__ unsigned int h2u(__half2 h) { return __builtin_bit_cast(unsigned int, h); }

// ---------------------------------------------------------------------------
// K0: prep all weight transforms once.
//   i <  51200 : wt bf16 [64][800]      (fc1w, K zero-padded)
//   i <  52736 : A_f16 [12][16][8]      (W2 MFMA-A layout, f16, slots 9..11 = 0)
//   i <  52808 : w1h2 [72] u32          (half2(w,w) duplicated conv1 weights)
//   i <  52816 : b1h2 [8] u32           (half2(b,b))
// ---------------------------------------------------------------------------
__global__ __launch_bounds__(256) void k_prep(
    const float* __restrict__ fc1w, const float* __restrict__ w2,
    const float* __restrict__ w1, const float* __restrict__ b1,
    unsigned short* __restrict__ wt, unsigned short* __restrict__ af16,
    unsigned int* __restrict__ w1h2, unsigned int* __restrict__ b1h2)
{
    int i = blockIdx.x * 256 + threadIdx.x;
    if (i < 51200) {
        int n = i / 800, k = i - n * 800;
        float v = (k < 787) ? fc1w[n * 787 + k] : 0.f;
        wt[i] = f2bf(v);
    } else if (i < 52736) {
        int a = i - 51200;
        int slot = a >> 7, rem = a & 127, oc = rem >> 3, ic = rem & 7;
        float v = (slot < 9) ? w2[oc * 72 + ic * 9 + slot] : 0.f;
        af16[a] = __half_as_ushort(__float2half(v));
    } else if (i < 52808) {
        int k = i - 52736;
        unsigned int hb = __half_as_ushort(__float2half(w1[k]));
        w1h2[k] = hb | (hb << 16);
    } else if (i < 52816) {
        int k = i - 52808;
        unsigned int hb = __half_as_ushort(__float2half(b1[k]));
        b1h2[k] = hb | (hb << 16);
    }
}

// ---------------------------------------------------------------------------
// K1: wave-per-image, barrier-free. Each wave owns a private LDS slice and
//     processes IMGW images start-to-finish (conv1 packed f16, conv2 f16 MFMA,
//     filter conv packed f16, sampler, bf16 pack). One __syncthreads total
//     (after block-shared small-weight staging).
// ---------------------------------------------------------------------------
__global__ __launch_bounds__(256) void k_conv(
    const float* __restrict__ x,
    const float* __restrict__ s1w, const float* __restrict__ s1b,
    const float* __restrict__ s2w, const float* __restrict__ s2b,
    const float* __restrict__ fw, const float* __restrict__ fb,
    const float* __restrict__ b2,
    const unsigned short* __restrict__ Afg,   // [12][16][8] f16
    const unsigned int* __restrict__ w1h2g,   // [72]
    const unsigned int* __restrict__ b1h2g,   // [8]
    unsigned short* __restrict__ comb)
{
    const int t = threadIdx.x;
    const int w = t >> 6, l = t & 63;

    // per-wave private slices
    __shared__ unsigned int sxu_all[4][30 * 18];                 // f16 col-pairs, stride 18 u32
    __shared__ __align__(16) unsigned short sf1_all[4][16 * 136]; // conv1 pooled, channels-last f16
    __shared__ __align__(16) float scomb_all[4][800];
    __shared__ float ssm[27];   // s1w(8) s1b(4) s2w(8) s2b(2) fw(4) fb(1)
    __shared__ float sb2s[16];

    unsigned int* sxu = sxu_all[w];
    unsigned short* sf1 = sf1_all[w];
    float* scomb = scomb_all[w];

    // ---- block prologue: tiny shared weights, one barrier ------------------
    if (t < 8) ssm[t] = s1w[t];
    else if (t < 12) ssm[t] = s1b[t - 8];
    else if (t < 20) ssm[t] = s2w[t - 12];
    else if (t < 22) ssm[t] = s2b[t - 20];
    else if (t < 26) ssm[t] = fw[t - 22];
    else if (t == 26) ssm[26] = fb[0];
    if (t >= 32 && t < 48) sb2s[t - 32] = b2[t - 32];
    __syncthreads();

    // ---- per-wave init -----------------------------------------------------
    for (int i = l; i < 540; i += 64) sxu[i] = 0u;
    if (l < 60) {   // sf1 pad ring
        int R, C;
        if (l < 16)      { R = 0;      C = l; }
        else if (l < 32) { R = 15;     C = l - 16; }
        else if (l < 46) { R = l - 31; C = 0; }
        else             { R = l - 45; C = 15; }
        *reinterpret_cast<uint4*>(&sf1[R * 136 + C * 8]) = uint4{0u, 0u, 0u, 0u};
    }
    if (l < 16) scomb[784 + l] = 0.f;

    const __half2 fwh0 = __float2half2_rn(ssm[22]);
    const __half2 fwh1 = __float2half2_rn(ssm[23]);
    const __half2 fwh2 = __float2half2_rn(ssm[24]);
    const __half2 fwh3 = __float2half2_rn(ssm[25]);
    const __half2 fbh  = __float2half2_rn(ssm[26]);

    // conv2 MFMA lane constants (invariant across images)
    const int n = l & 15, g = l >> 4;
    const int qr = n & 7;
    const int q = (qr < 7) ? qr : 6;       // clamp dead lane
    const int dr = n >> 3;
    int offs[3];
    VH af[3];
    #pragma unroll
    for (int s = 0; s < 3; ++s) {
        const int slot = s * 4 + g;
        const int u = slot / 3, v = slot - 3 * (slot / 3);
        offs[s] = (slot <= 8) ? (u * 136 + v * 8) : 0;
        af[s].u = *reinterpret_cast<const uint4*>(Afg + ((slot * 16 + n) << 3));
    }

    // ---- image loop (no barriers; wave-private LDS, in-order DS pipe) ------
    #pragma unroll 1
    for (int img = 0; img < IMGW; ++img) {
        const int b = (blockIdx.x * 4 + w) * IMGW + img;
        const float* xb = x + (size_t)b * 784;

        // stage x -> f16 col-pairs (28 rows x 15 u32 units)
        for (int u0 = l; u0 < 420; u0 += 64) {
            int r = u0 / 15, ww = u0 - (u0 / 15) * 15;
            __half2 h2;
            if (ww == 0)       h2 = __floats2half2_rn(0.f, xb[r * 28]);
            else if (ww == 14) h2 = __floats2half2_rn(xb[r * 28 + 27], 0.f);
            else               h2 = __floats2half2_rn(xb[r * 28 + 2 * ww - 1],
                                                      xb[r * 28 + 2 * ww]);
            sxu[(r + 1) * 18 + ww] = h2u(h2);
        }

        // filter conv (2 positions per unit, packed f16) + sigmoid wave-sum
        float fsum = 0.f;
        for (int u0 = l; u0 < 378; u0 += 64) {
            int r = u0 / 14, cp = u0 - (u0 / 14) * 14;
            unsigned int A1 = sxu[(r + 1) * 18 + cp], B1 = sxu[(r + 1) * 18 + cp + 1];
            unsigned int A2 = sxu[(r + 2) * 18 + cp], B2 = sxu[(r + 2) * 18 + cp + 1];
            __half2 al1 = u2h(__builtin_amdgcn_alignbit(B1, A1, 16));
            __half2 al2 = u2h(__builtin_amdgcn_alignbit(B2, A2, 16));
            __half2 acc = __hfma2(fwh0, al1,
                          __hfma2(fwh1, u2h(B1),
                          __hfma2(fwh2, al2,
                          __hfma2(fwh3, u2h(B2), fbh))));
            float2 f = __half22float2(acc);
            fsum += __frcp_rn(1.f + __expf(-f.x));
            if (cp < 13) fsum += __frcp_rn(1.f + __expf(-f.y));
        }
        #pragma unroll
        for (int off = 32; off > 0; off >>= 1)
            fsum += __shfl_xor(fsum, off, 64);

        // conv1: pooled cell (p,j), 8 oc, packed f16
        for (int i = l; i < 196; i += 64) {
            const int p = i / 14, j = i - (i / 14) * 14;
            unsigned int A[4], B[4], M[4];
            #pragma unroll
            for (int u = 0; u < 4; ++u) {
                A[u] = sxu[(2 * p + u) * 18 + j];
                B[u] = sxu[(2 * p + u) * 18 + j + 1];
                M[u] = __builtin_amdgcn_alignbit(B[u], A[u], 16);
            }
            unsigned short outv[8];
            #pragma unroll
            for (int oc = 0; oc < 8; ++oc) {
                __half2 a0 = u2h(b1h2g[oc]), a1 = a0;
                #pragma unroll
                for (int u = 0; u < 3; ++u) {
                    #pragma unroll
                    for (int v = 0; v < 3; ++v) {
                        const __half2 wv = u2h(w1h2g[oc * 9 + u * 3 + v]);
                        const unsigned int p0 = (v == 0) ? A[u]     : ((v == 1) ? M[u]     : B[u]);
                        const unsigned int p1 = (v == 0) ? A[u + 1] : ((v == 1) ? M[u + 1] : B[u + 1]);
                        a0 = __hfma2(wv, u2h(p0), a0);
                        a1 = __hfma2(wv, u2h(p1), a1);
                    }
                }
                short2v s0 = __builtin_bit_cast(short2v, a0);
                short2v s1 = __builtin_bit_cast(short2v, a1);
                short2v mm = __builtin_elementwise_max(s0, s1);
                short m = mm[0] > mm[1] ? mm[0] : mm[1];
                if (m < 0) m = 0;
                outv[oc] = (unsigned short)m;
            }
            *reinterpret_cast<uint4*>(&sf1[(p + 1) * 136 + (j + 1) * 8]) =
                *reinterpret_cast<const uint4*>(outv);
        }

        // conv2 via f16 MFMA: whole image in this wave (pp = 0..6)
        for (int pp = 0; pp < 7; ++pp) {
            const int rbase = (2 * pp + dr) * 136 + (2 * q) * 8;
            f32x4 acc0 = {0.f, 0.f, 0.f, 0.f}, acc1 = {0.f, 0.f, 0.f, 0.f};
            #pragma unroll
            for (int s = 0; s < 3; ++s) {
                VH b0, b1v;
                b0.u  = *reinterpret_cast<const uint4*>(&sf1[rbase + offs[s]]);
                b1v.u = *reinterpret_cast<const uint4*>(&sf1[rbase + 8 + offs[s]]);
                acc0 = __builtin_amdgcn_mfma_f32_16x16x32_f16(af[s].h, b0.h, acc0, 0, 0, 0);
                acc1 = __builtin_amdgcn_mfma_f32_16x16x32_f16(af[s].h, b1v.h, acc1, 0, 0, 0);
            }
            #pragma unroll
            for (int i = 0; i < 4; ++i) {
                const float bias = sb2s[4 * g + i];
                float m = fmaxf(acc0[i], acc1[i]);            // max over dc
                m = fmaxf(m, __shfl_xor(m, 8, 64));           // max over dr
                if (n < 7)
                    scomb[(4 * g + i) * 49 + pp * 7 + q] = fmaxf(m + bias, 0.f);
            }
        }

        // sampler + filter-mean finalize (lane 0; other waves fill the SIMD)
        if (l == 0) {
            scomb[786] = fsum * (1.f / 729.f);
            float f0 = scomb[0], f1 = scomb[1];
            float h[4];
            #pragma unroll
            for (int k = 0; k < 4; ++k) {
                float y = fmaf(f0, ssm[k * 2], fmaf(f1, ssm[k * 2 + 1], ssm[8 + k]));
                float e = __expf(2.f * y);
                h[k] = (e - 1.f) * __frcp_rn(e + 1.f);
            }
            float l0 = ssm[20], l1 = ssm[21];
            #pragma unroll
            for (int k = 0; k < 4; ++k) {
                l0 = fmaf(h[k], ssm[12 + k], l0);
                l1 = fmaf(h[k], ssm[16 + k], l1);
            }
            float mx = fmaxf(l0, l1);
            float e0 = __expf(l0 - mx), e1 = __expf(l1 - mx);
            float inv = __frcp_rn(e0 + e1);
            scomb[784] = e0 * inv;
            scomb[785] = e1 * inv;
        }

        // pack scomb -> combined bf16 row [800]
        for (int u = l; u < 100; u += 64) {
            const float4* sp = reinterpret_cast<const float4*>(scomb);
            float4 f0 = sp[2 * u], f1 = sp[2 * u + 1];
            uint4 o;
            o.x = (unsigned int)f2bf(f0.x) | ((unsigned int)f2bf(f0.y) << 16);
            o.y = (unsigned int)f2bf(f0.z) | ((unsigned int)f2bf(f0.w) << 16);
            o.z = (unsigned int)f2bf(f1.x) | ((unsigned int)f2bf(f1.y) << 16);
            o.w = (unsigned int)f2bf(f1.z) | ((unsigned int)f2bf(f1.w) << 16);
            reinterpret_cast<uint4*>(comb)[(size_t)b * 100 + u] = o;
        }
    }
}

// ---------------------------------------------------------------------------
// K2: MFMA GEMM  h1 = relu(comb[16384,800] @ wt[64,800]^T + fc1b)
//     epilogue: out = h1 @ fc2w^T + fc2b  (+ per-block BN partial stats)
// ---------------------------------------------------------------------------
__global__ __launch_bounds__(256) void k_fc(
    const unsigned short* __restrict__ A,
    const unsigned short* __restrict__ Bw,
    const float* __restrict__ fc1b,
    const float* __restrict__ fc2w, const float* __restrict__ fc2b,
    float* __restrict__ out, float* __restrict__ part)
{
    __shared__ uint4 Asm[2][256];
    __shared__ uint4 Bsm[2][256];
    __shared__ float sh[64][68];
    __shared__ float sfc2[4][64];
    __shared__ float pacc[4][8];

    const int t = threadIdx.x;
    const int w = t >> 6, l = t & 63;
    const int blk = blockIdx.x;

    sfc2[t >> 6][t & 63] = fc2w[t];

    const int srow = t >> 2, skbp = t & 3;
    const int skbl = skbp ^ ((srow >> 1) & 3);
    const uint4* Ag = reinterpret_cast<const uint4*>(A) + ((size_t)blk * 64 + srow) * 100;
    const uint4* Bg = reinterpret_cast<const uint4*>(Bw) + (size_t)srow * 100;
    const int sidx = srow * 4 + skbp;

    const int arow = w * 16 + (l & 15);
    const int aidx = arow * 4 + ((l >> 4) ^ ((arow >> 1) & 3));
    int bidx[4];
    #pragma unroll
    for (int nf = 0; nf < 4; ++nf) {
        int nn = nf * 16 + (l & 15);
        bidx[nf] = nn * 4 + ((l >> 4) ^ ((nn >> 1) & 3));
    }

    f32x4 acc0 = {0.f, 0.f, 0.f, 0.f}, acc1 = acc0, acc2 = acc0, acc3 = acc0;

    Asm[0][sidx] = Ag[skbl];
    Bsm[0][sidx] = Bg[skbl];

    int buf = 0;
    for (int s = 0; s < 25; ++s) {
        __syncthreads();
        if (s < 24) {
            Asm[buf ^ 1][sidx] = Ag[(s + 1) * 4 + skbl];
            Bsm[buf ^ 1][sidx] = Bg[(s + 1) * 4 + skbl];
        }
        V8 av; av.u = Asm[buf][aidx];
        V8 b0; b0.u = Bsm[buf][bidx[0]];
        V8 b1; b1.u = Bsm[buf][bidx[1]];
        V8 b2; b2.u = Bsm[buf][bidx[2]];
        V8 b3; b3.u = Bsm[buf][bidx[3]];
        acc0 = __builtin_amdgcn_mfma_f32_16x16x32_bf16(av.s, b0.s, acc0, 0, 0, 0);
        acc1 = __builtin_amdgcn_mfma_f32_16x16x32_bf16(av.s, b1.s, acc1, 0, 0, 0);
        acc2 = __builtin_amdgcn_mfma_f32_16x16x32_bf16(av.s, b2.s, acc2, 0, 0, 0);
        acc3 = __builtin_amdgcn_mfma_f32_16x16x32_bf16(av.s, b3.s, acc3, 0, 0, 0);
        buf ^= 1;
    }

    {
        const int c0 = l & 15, r0 = w * 16 + (l >> 4) * 4;
        float fb0 = fc1b[c0], fb1 = fc1b[16 + c0], fb2 = fc1b[32 + c0], fb3 = fc1b[48 + c0];
        #pragma unroll
        for (int r = 0; r < 4; ++r) {
            sh[r0 + r][c0]      = fmaxf(acc0[r] + fb0, 0.f);
            sh[r0 + r][16 + c0] = fmaxf(acc1[r] + fb1, 0.f);
            sh[r0 + r][32 + c0] = fmaxf(acc2[r] + fb2, 0.f);
            sh[r0 + r][48 + c0] = fmaxf(acc3[r] + fb3, 0.f);
        }
    }
    __syncthreads();

    {
        const int row = t >> 2, oo = t & 3;
        float s = fc2b[oo];
        #pragma unroll 8
        for (int o = 0; o < 64; ++o)
            s = fmaf(sh[row][o], sfc2[oo][o], s);
        out[((size_t)blk * 64 + row) * 4 + oo] = s;

        float rs = s, rq = s * s;
        #pragma unroll
        for (int off = 4; off < 64; off <<= 1) {
            rs += __shfl_xor(rs, off, 64);
            rq += __shfl_xor(rq, off, 64);
        }
        if (l < 4) pacc[w][l] = rs;
        else if (l < 8) pacc[w][l] = rq;
    }
    __syncthreads();
    if (t < 8)
        part[blk * 8 + t] = pacc[0][t] + pacc[1][t] + pacc[2][t] + pacc[3][t];
}

// ---------------------------------------------------------------------------
// BN finalize + apply
// ---------------------------------------------------------------------------
__global__ void k_bnfinal(const float* __restrict__ part,
                          const float* __restrict__ g, const float* __restrict__ bb,
                          float* __restrict__ ss, int nblocks)
{
    const int t = threadIdx.x;  // 64
    float s[8];
    #pragma unroll
    for (int i = 0; i < 8; ++i) s[i] = 0.f;
    for (int idx = t; idx < nblocks; idx += 64)
        #pragma unroll
        for (int i = 0; i < 8; ++i) s[i] += part[idx * 8 + i];
    #pragma unroll
    for (int i = 0; i < 8; ++i)
        #pragma unroll
        for (int off = 32; off > 0; off >>= 1)
            s[i] += __shfl_xor(s[i], off, 64);
    if (t == 0) {
        const float invB = 1.f / 16384.f;
        #pragma unroll
        for (int j = 0; j < 4; ++j) {
            float mu = s[j] * invB;
            float var = s[4 + j] * invB - mu * mu;
            float sc = g[j] * rsqrtf(var + EPSV);
            ss[j] = sc;
            ss[4 + j] = bb[j] - mu * sc;
        }
    }
}

__global__ __launch_bounds__(256) void k_bnapply(const float* __restrict__ ss,
                                                 float* __restrict__ out)
{
    const int row = blockIdx.x * 256 + threadIdx.x;
    float4 v = reinterpret_cast<float4*>(out)[row];
    v.x = fmaf(v.x, ss[0], ss[4]);
    v.y = fmaf(v.y, ss[1], ss[5]);
    v.z = fmaf(v.z, ss[2], ss[6]);
    v.w = fmaf(v.w, ss[3], ss[7]);
    reinterpret_cast<float4*>(out)[row] = v;
}

// ===========================================================================
// Fallback path (round-2 kernels) — used if ws_size is too small
// ===========================================================================
__global__ __launch_bounds__(256) void k_transpose_fb(const float* __restrict__ in,
                                                      float* __restrict__ out)
{
    int i = blockIdx.x * 256 + threadIdx.x;
    if (i < 787 * 64) {
        int k = i >> 6, o = i & 63;
        out[i] = in[o * 787 + k];
    }
}

#define SF1F(ic, r, c) sf1[(ic) * 324 + (r) * 20 + (c)]

__global__ __launch_bounds__(256) void k_fused_fb(
    const float* __restrict__ x,
    const float* __restrict__ w1, const float* __restrict__ b1,
    const float* __restrict__ w2, const float* __restrict__ b2,
    const float* __restrict__ s1w, const float* __restrict__ s1b,
    const float* __restrict__ s2w, const float* __restrict__ s2b,
    const float* __restrict__ fw, const float* __restrict__ fb,
    const float* __restrict__ wt, const float* __restrict__ fc1b,
    const float* __restrict__ fc2w, const float* __restrict__ fc2b,
    float* __restrict__ pre)
{
    const int b = blockIdx.x;
    const int t = threadIdx.x;

    __shared__ float sxA[30][20];
    __shared__ float sxB[30][20];
    __shared__ float sf1[8 * 324];
    __shared__ float scomb[788];
    __shared__ float sw1[72];
    __shared__ float sb1[8];
    __shared__ float sw2p[16 * 76];
    __shared__ float sb2[16];
    __shared__ float sh1p[4][64];
    __shared__ float sh1[64];
    __shared__ float sred[4];
    __shared__ float ssm[27];

    for (int i = t; i < 600; i += 256) { (&sxA[0][0])[i] = 0.f; (&sxB[0][0])[i] = 0.f; }
    for (int i = t; i < 8 * 324; i += 256) sf1[i] = 0.f;
    if (t < 72) sw1[t] = w1[t];
    if (t < 8) sb1[t] = b1[t];
    for (int i = t; i < 1152; i += 256) {
        int oc = i / 72, rem = i - oc * 72;
        sw2p[oc * 76 + rem] = w2[i];
    }
    if (t < 16) sb2[t] = b2[t];
    if (t < 8) ssm[t] = s1w[t];
    else if (t < 12) ssm[t] = s1b[t - 8];
    else if (t < 20) ssm[t] = s2w[t - 12];
    else if (t < 22) ssm[t] = s2b[t - 20];
    else if (t < 26) ssm[t] = fw[t - 22];
    else if (t == 26) ssm[t] = fb[0];
    __syncthreads();

    const float* xb = x + (size_t)b * 784;
    for (int i = t; i < 784; i += 256) {
        int r = i / 28, c = i - (i / 28) * 28;
        float v = xb[i];
        int pr = r + 1, pc = c + 1;
        if (pc <= 15) sxA[pr][pc] = v;
        if (pc >= 14) sxB[pr][pc - 14] = v;
    }
    __syncthreads();

    {
        const float fw00 = ssm[22], fw01 = ssm[23], fw10 = ssm[24], fw11 = ssm[25];
        const float fbv = ssm[26];
        float fsum = 0.f;
        for (int i = t; i < 729; i += 256) {
            int r = i / 27, c = i - (i / 27) * 27;
            float x00, x01, x10, x11;
            if (c <= 13) {
                x00 = sxA[r + 1][c + 1]; x01 = sxA[r + 1][c + 2];
                x10 = sxA[r + 2][c + 1]; x11 = sxA[r + 2][c + 2];
            } else {
                int cb = c - 14;
                x00 = sxB[r + 1][cb + 1]; x01 = sxB[r + 1][cb + 2];
                x10 = sxB[r + 2][cb + 1]; x11 = sxB[r + 2][cb + 2];
            }
            float v = fbv;
            v = fmaf(x00, fw00, v); v = fmaf(x01, fw01, v);
            v = fmaf(x10, fw10, v); v = fmaf(x11, fw11, v);
            fsum += 1.f / (1.f + expf(-v));
        }
        #pragma unroll
        for (int off = 32; off > 0; off >>= 1)
            fsum += __shfl_xor(fsum, off, 64);
        if ((t & 63) == 0) sred[t >> 6] = fsum;
    }

    {
        const int half = t >> 7;
        const int id = t & 127;
        if (id < 112) {
            const int p = id >> 3, oc = id & 7;
            const float* base = half ? &sxB[0][0] : &sxA[0][0];
            float X[4][16];
            #pragma unroll
            for (int u = 0; u < 4; ++u) {
                const float4* rp = reinterpret_cast<const float4*>(base + (2 * p + u) * 20);
                float4 a = rp[0], bb4 = rp[1], c4 = rp[2], d4 = rp[3];
                X[u][0] = a.x;  X[u][1] = a.y;  X[u][2] = a.z;  X[u][3] = a.w;
                X[u][4] = bb4.x; X[u][5] = bb4.y; X[u][6] = bb4.z; X[u][7] = bb4.w;
                X[u][8] = c4.x;  X[u][9] = c4.y;  X[u][10] = c4.z; X[u][11] = c4.w;
                X[u][12] = d4.x; X[u][13] = d4.y; X[u][14] = d4.z; X[u][15] = d4.w;
            }
            float W[9];
            #pragma unroll
            for (int k = 0; k < 9; ++k) W[k] = sw1[oc * 9 + k];
            const float bias = sb1[oc];
            const int j0 = half * 7;
            #pragma unroll
            for (int jj = 0; jj < 7; ++jj) {
                float m = 0.f;
                #pragma unroll
                for (int dr = 0; dr < 2; ++dr)
                    #pragma unroll
                    for (int dc = 0; dc < 2; ++dc) {
                        float acc = bias;
                        #pragma unroll
                        for (int u = 0; u < 3; ++u)
                            #pragma unroll
                            for (int v = 0; v < 3; ++v)
                                acc = fmaf(X[dr + u][2 * jj + dc + v], W[u * 3 + v], acc);
                        m = fmaxf(m, acc);
                    }
                SF1F(oc, p + 1, j0 + jj + 1) = m;
            }
        }
    }
    __syncthreads();

    if (t < 112) {
        const int p = t >> 4, oc = t & 15;
        const float bias = sb2[oc];
        float acc[7][4];
        #pragma unroll
        for (int jj = 0; jj < 7; ++jj)
            #pragma unroll
            for (int s = 0; s < 4; ++s) acc[jj][s] = bias;
        for (int ic = 0; ic < 8; ++ic) {
            float X[4][16];
            #pragma unroll
            for (int u = 0; u < 4; ++u) {
                const float4* rp = reinterpret_cast<const float4*>(&SF1F(ic, 2 * p + u, 0));
                float4 a = rp[0], bb4 = rp[1], c4 = rp[2], d4 = rp[3];
                X[u][0] = a.x;  X[u][1] = a.y;  X[u][2] = a.z;  X[u][3] = a.w;
                X[u][4] = bb4.x; X[u][5] = bb4.y; X[u][6] = bb4.z; X[u][7] = bb4.w;
                X[u][8] = c4.x;  X[u][9] = c4.y;  X[u][10] = c4.z; X[u][11] = c4.w;
                X[u][12] = d4.x; X[u][13] = d4.y; X[u][14] = d4.z; X[u][15] = d4.w;
            }
            float W[9];
            #pragma unroll
            for (int k = 0; k < 9; ++k) W[k] = sw2p[oc * 76 + ic * 9 + k];
            #pragma unroll
            for (int jj = 0; jj < 7; ++jj)
                #pragma unroll
                for (int dr = 0; dr < 2; ++dr)
                    #pragma unroll
                    for (int dc = 0; dc < 2; ++dc)
                        #pragma unroll
                        for (int u = 0; u < 3; ++u)
                            #pragma unroll
                            for (int v = 0; v < 3; ++v)
                                acc[jj][dr * 2 + dc] =
                                    fmaf(X[dr + u][2 * jj + dc + v], W[u * 3 + v], acc[jj][dr * 2 + dc]);
        }
        #pragma unroll
        for (int jj = 0; jj < 7; ++jj) {
            float m = fmaxf(fmaxf(acc[jj][0], acc[jj][1]), fmaxf(acc[jj][2], acc[jj][3]));
            scomb[oc * 49 + p * 7 + jj] = fmaxf(m, 0.f);
        }
    }
    __syncthreads();

    if (t == 0) {
        scomb[786] = (sred[0] + sred[1] + sred[2] + sred[3]) * (1.f / 729.f);
        float f0 = scomb[0], f1 = scomb[1];
        float h[4];
        #pragma unroll
        for (int k = 0; k < 4; ++k)
            h[k] = tanhf(fmaf(f0, ssm[k * 2], fmaf(f1, ssm[k * 2 + 1], ssm[8 + k])));
        float l0 = ssm[20], l1 = ssm[21];
        #pragma unroll
        for (int k = 0; k < 4; ++k) {
            l0 = fmaf(h[k], ssm[12 + k], l0);
            l1 = fmaf(h[k], ssm[16 + k], l1);
        }
        float mx = fmaxf(l0, l1);
        float e0 = expf(l0 - mx), e1 = expf(l1 - mx);
        float inv = 1.f / (e0 + e1);
        scomb[784] = e0 * inv;
        scomb[785] = e1 * inv;
    }
    __syncthreads();

    {
        const int o = t & 63, w = t >> 6;
        const int k0 = w * 197;
        const int k1 = (w == 3) ? 787 : k0 + 197;
        const float* wp = wt + (size_t)k0 * 64 + o;
        float acc = 0.f;
        #pragma unroll 4
        for (int k = k0; k < k1; ++k) {
            acc = fmaf(scomb[k], *wp, acc);
            wp += 64;
        }
        sh1p[w][o] = acc;
    }
    __syncthreads();
    if (t < 64)
        sh1[t] = fmaxf(sh1p[0][t] + sh1p[1][t] + sh1p[2][t] + sh1p[3][t] + fc1b[t], 0.f);
    __syncthreads();

    {
        const int oo = t >> 6, lane = t & 63;
        float v = sh1[lane] * fc2w[oo * 64 + lane];
        #pragma unroll
        for (int off = 32; off > 0; off >>= 1)
            v += __shfl_xor(v, off, 64);
        if (lane == 0) pre[(size_t)b * 4 + oo] = v + fc2b[oo];
    }
}

__global__ __launch_bounds__(256) void k_bnstat_fb(const float* __restrict__ pre,
                                                   float* __restrict__ part)
{
    const int t = threadIdx.x;
    const int row = blockIdx.x * 256 + t;
    float4 v = reinterpret_cast<const float4*>(pre)[row];
    float s0 = v.x, s1 = v.y, s2 = v.z, s3 = v.w;
    float q0 = v.x * v.x, q1 = v.y * v.y, q2 = v.z * v.z, q3 = v.w * v.w;
    #pragma unroll
    for (int off = 32; off > 0; off >>= 1) {
        s0 += __shfl_xor(s0, off, 64);
        s1 += __shfl_xor(s1, off, 64);
        s2 += __shfl_xor(s2, off, 64);
        s3 += __shfl_xor(s3, off, 64);
        q0 += __shfl_xor(q0, off, 64);
        q1 += __shfl_xor(q1, off, 64);
        q2 += __shfl_xor(q2, off, 64);
        q3 += __shfl_xor(q3, off, 64);
    }
    __shared__ float acc[4][8];
    if ((t & 63) == 0) {
        int w = t >> 6;
        acc[w][0] = s0; acc[w][1] = s1; acc[w][2] = s2; acc[w][3] = s3;
        acc[w][4] = q0; acc[w][5] = q1; acc[w][6] = q2; acc[w][7] = q3;
    }
    __syncthreads();
    if (t < 8)
        part[blockIdx.x * 8 + t] = acc[0][t] + acc[1][t] + acc[2][t] + acc[3][t];
}

// ===========================================================================
extern "C" void kernel_launch(void* const* d_in, const int* in_sizes, int n_in,
                              void* d_out, int out_size, void* d_ws, size_t ws_size,
                              hipStream_t stream)
{
    const float* x    = (const float*)d_in[0];
    const float* w1   = (const float*)d_in[1];
    const float* b1   = (const float*)d_in[2];
    const float* w2   = (const float*)d_in[3];
    const float* b2   = (const float*)d_in[4];
    const float* s1w  = (const float*)d_in[5];
    const float* s1b  = (const float*)d_in[6];
    const float* s2w  = (const float*)d_in[7];
    const float* s2b  = (const float*)d_in[8];
    const float* fw   = (const float*)d_in[9];
    const float* fb   = (const float*)d_in[10];
    const float* fc1w = (const float*)d_in[11];
    const float* fc1b = (const float*)d_in[12];
    const float* fc2w = (const float*)d_in[13];
    const float* fc2b = (const float*)d_in[14];
    const float* bng  = (const float*)d_in[15];
    const float* bnb  = (const float*)d_in[16];

    float* out = (float*)d_out;

    const size_t COMB_BYTES = (size_t)NBATCH * 800 * 2;      // 26,214,400
    const size_t WT_BYTES   = 64 * 800 * 2;                  // 102,400
    const size_t AF16_BYTES = 1536 * 2;                      // 3,072
    const size_t W1H2_BYTES = 72 * 4;                        // 288
    const size_t B1H2_BYTES = 8 * 4;                         // 32
    const size_t PART_BYTES = 256 * 8 * 4;                   // 8,192
    const size_t NEED = COMB_BYTES + WT_BYTES + AF16_BYTES + W1H2_BYTES +
                        B1H2_BYTES + PART_BYTES + 32;

    if (ws_size >= NEED) {
        char* p = (char*)d_ws;
        unsigned short* comb = (unsigned short*)p;                     p += COMB_BYTES;
        unsigned short* wtbf = (unsigned short*)p;                     p += WT_BYTES;
        unsigned short* af16 = (unsigned short*)p;                     p += AF16_BYTES;
        unsigned int*   w1h2 = (unsigned int*)p;                       p += W1H2_BYTES;
        unsigned int*   b1h2 = (unsigned int*)p;                       p += B1H2_BYTES;
        float*          part = (float*)p;                              p += PART_BYTES;
        float*          ss   = (float*)p;

        k_prep<<<207, 256, 0, stream>>>(fc1w, w2, w1, b1, wtbf, af16, w1h2, b1h2);
        k_conv<<<NBATCH / (4 * IMGW), 256, 0, stream>>>(x, s1w, s1b, s2w, s2b, fw, fb, b2,
                                                        af16, w1h2, b1h2, comb);
        k_fc<<<256, 256, 0, stream>>>(comb, wtbf, fc1b, fc2w, fc2b, out, part);
        k_bnfinal<<<1, 64, 0, stream>>>(part, bng, bnb, ss, 256);
        k_bnapply<<<64, 256, 0, stream>>>(ss, out);
    } else {
        float* part = (float*)d_ws;
        float* ss   = part + 512;
        float* wt   = ss + 8;

        k_transpose_fb<<<197, 256, 0, stream>>>(fc1w, wt);
        k_fused_fb<<<NBATCH, 256, 0, stream>>>(x, w1, b1, w2, b2, s1w, s1b, s2w, s2b,
                                               fw, fb, wt, fc1b, fc2w, fc2b, out);
        k_bnstat_fb<<<64, 256, 0, stream>>>(out, part);
        k_bnfinal<<<1, 64, 0, stream>>>(part, bng, bnb, ss, 64);
        k_bnapply<<<64, 256, 0, stream>>>(ss, out);
    }
}